// Round 10
// baseline (356.766 us; speedup 1.0000x reference)
//
#include <hip/hip_runtime.h>
#include <cstdint>
#include <cstddef>

#define NEG_SLOPE 0.2f

// Edge packing relies on N <= 65536 (here N = 50000): edge = src | (dst<<16).
// Self-loops are NOT sorted: placed analytically (one per node, first slot).
// csrc[] stores the PACKED edge (src in low 16, dst in high 16).
#define NB 512        // nodes per bucket
#define LOG_NB 9
#define MAXK 512

__device__ inline unsigned short f2bf(float f) {          // RNE fp32->bf16
    unsigned int u = __float_as_uint(f);
    u += 0x7FFFu + ((u >> 16) & 1u);
    return (unsigned short)(u >> 16);
}
__device__ inline float bf_lo(unsigned int u) { return __uint_as_float(u << 16); }
__device__ inline float bf_hi(unsigned int u) { return __uint_as_float(u & 0xFFFF0000u); }
__device__ inline unsigned int pk2bf(float lo, float hi) {
    return (unsigned int)f2bf(lo) | ((unsigned int)f2bf(hi) << 16);
}

// ---------------- P1: per-block bucket histogram (real edges only) ----------------
__global__ __launch_bounds__(256) void sort_count_kernel(const int* __restrict__ ei, int E,
                                                         int K, int CH, int* __restrict__ bcnt) {
    __shared__ int hist[MAXK];
    int tid = threadIdx.x;
    for (int i = tid; i < K; i += 256) hist[i] = 0;
    __syncthreads();
    int lo = blockIdx.x * CH;
    int hi = lo + CH; if (hi > E) hi = E;
    for (int e = lo + tid; e < hi; e += 256)
        atomicAdd(&hist[ei[(size_t)E + e] >> LOG_NB], 1);
    __syncthreads();
    for (int i = tid; i < K; i += 256)
        if (hist[i]) atomicAdd(&bcnt[i], hist[i]);
}

// ---------------- P2: scan bucket counts ----------------
__global__ void sort_scan_kernel(const int* __restrict__ bcnt, int* __restrict__ boff,
                                 int* __restrict__ bcur, int K, int E) {
    __shared__ int buf[MAXK];
    int tid = threadIdx.x;   // 512 threads
    int v = (tid < K) ? bcnt[tid] : 0;
    buf[tid] = v;
    __syncthreads();
    for (int o = 1; o < MAXK; o <<= 1) {
        int t = (tid >= o) ? buf[tid - o] : 0;
        __syncthreads();
        buf[tid] += t;
        __syncthreads();
    }
    if (tid < K) {
        int ex = buf[tid] - v;
        boff[tid] = ex;
        bcur[tid] = ex;
    }
    if (tid == K) boff[K] = E;
}

// ---------------- P3: scatter packed real edges into buckets ----------------
__global__ __launch_bounds__(256) void sort_scatter_kernel(const int* __restrict__ ei, int E,
                                                           int K, int CH, int* __restrict__ bcur,
                                                           unsigned int* __restrict__ bkt) {
    __shared__ int hist[MAXK];
    __shared__ int base[MAXK];
    int tid = threadIdx.x;
    for (int i = tid; i < K; i += 256) hist[i] = 0;
    __syncthreads();
    int lo = blockIdx.x * CH;
    int hi = lo + CH; if (hi > E) hi = E;
    for (int e = lo + tid; e < hi; e += 256)
        atomicAdd(&hist[ei[(size_t)E + e] >> LOG_NB], 1);
    __syncthreads();
    for (int i = tid; i < K; i += 256) {
        int c = hist[i];
        base[i] = c ? atomicAdd(&bcur[i], c) : 0;
    }
    __syncthreads();
    for (int i = tid; i < K; i += 256) hist[i] = 0;
    __syncthreads();
    for (int e = lo + tid; e < hi; e += 256) {
        int s = ei[e];
        int d = ei[(size_t)E + e];
        int k = d >> LOG_NB;
        int r = atomicAdd(&hist[k], 1);
        bkt[(size_t)base[k] + r] = (unsigned int)s | ((unsigned int)d << 16);
    }
}

// ---------------- P4: per-bucket CSR finalize (parallel prefix; +1 self slot per node) ----------------
__global__ __launch_bounds__(256) void sort_finalize_kernel(const unsigned int* __restrict__ bkt,
                                                            const int* __restrict__ boff,
                                                            int* __restrict__ off,
                                                            unsigned int* __restrict__ csrc, int N) {
    __shared__ int nhist[NB];
    __shared__ int part[256];
    __shared__ int loff[NB];
    int k = blockIdx.x;
    int tid = threadIdx.x;
    int node0 = k << LOG_NB;
    int nh = N - node0; if (nh > NB) nh = NB;
    int beg = boff[k], end = boff[k + 1];
    for (int i = tid; i < NB; i += 256) nhist[i] = 0;
    __syncthreads();
    for (int e = beg + tid; e < end; e += 256)
        atomicAdd(&nhist[(bkt[e] >> 16) - node0], 1);
    __syncthreads();
    int i0 = 2 * tid, i1 = 2 * tid + 1;
    int v0 = (i0 < nh) ? nhist[i0] + 1 : 0;
    int v1 = (i1 < nh) ? nhist[i1] + 1 : 0;
    part[tid] = v0 + v1;
    __syncthreads();
    for (int o = 1; o < 256; o <<= 1) {
        int t = (tid >= o) ? part[tid - o] : 0;
        __syncthreads();
        part[tid] += t;
        __syncthreads();
    }
    int gbase = beg + node0;   // node0 self slots precede this bucket
    int base = gbase + ((tid > 0) ? part[tid - 1] : 0);
    if (i0 < nh) loff[i0] = base;
    if (i1 < nh) loff[i1] = base + v0;
    __syncthreads();
    for (int i = tid; i < nh; i += 256) {
        int node = node0 + i;
        off[node] = loff[i];
        csrc[loff[i]] = (unsigned int)node | ((unsigned int)node << 16);  // self-loop first
        nhist[i] = loff[i] + 1;
    }
    if (node0 + nh == N && tid == 0) off[N] = gbase + part[255];
    __syncthreads();
    for (int e = beg + tid; e < end; e += 256) {
        unsigned int p = bkt[e];
        int pos = atomicAdd(&nhist[(p >> 16) - node0], 1);
        csrc[pos] = p;   // keep packed (src | dst<<16)
    }
}

// ---- GEMM + fused att dots, register-tiled 8 rows x 4 cols per thread ----
// BF16IN: input matrix is bf16 (layer 2 reads h1 in bf16).

template <int FOUT, int H, bool BF16IN>
__global__ __launch_bounds__(256) void gemm_att_kernel(const void* __restrict__ Xv,
                                                       const float* __restrict__ W,
                                                       const float* __restrict__ attS,
                                                       const float* __restrict__ attD,
                                                       unsigned short* __restrict__ Ybf,
                                                       float* __restrict__ as_,
                                                       float* __restrict__ ad_, int N) {
    constexpr int ROWS = 8192 / FOUT;   // 64 (F=128) or 128 (F=64)
    constexpr int CG   = FOUT / 4;
    __shared__ float sX[ROWS][68];      // +4 pad keeps rows 16B-aligned
    __shared__ float sW[64 * FOUT];
    int tid = threadIdx.x;
    int rowbase = blockIdx.x * ROWS;
    int cg = tid % CG;
    int rg = tid / CG;
    int r0 = rg * 8;

    float acc[8][4];
#pragma unroll
    for (int i = 0; i < 8; i++)
#pragma unroll
        for (int c = 0; c < 4; c++) acc[i][c] = 0.f;

    for (int k0 = 0; k0 < 128; k0 += 64) {
        __syncthreads();
        if (BF16IN) {
            const unsigned short* Xb = (const unsigned short*)Xv;
            for (int idx = tid; idx < ROWS * 8; idx += 256) {
                int r = idx >> 3, g = idx & 7;
                int row = rowbase + r;
                uint4 v = (row < N) ? *(const uint4*)&Xb[(size_t)row * 128 + k0 + g * 8]
                                    : make_uint4(0, 0, 0, 0);
                float* dst = &sX[r][g * 8];
                dst[0] = bf_lo(v.x); dst[1] = bf_hi(v.x);
                dst[2] = bf_lo(v.y); dst[3] = bf_hi(v.y);
                dst[4] = bf_lo(v.z); dst[5] = bf_hi(v.z);
                dst[6] = bf_lo(v.w); dst[7] = bf_hi(v.w);
            }
        } else {
            const float* X = (const float*)Xv;
            for (int idx = tid; idx < ROWS * 16; idx += 256) {
                int r = idx >> 4, q = idx & 15;
                int row = rowbase + r;
                float4 val = (row < N) ? *(const float4*)&X[(size_t)row * 128 + k0 + q * 4]
                                       : make_float4(0.f, 0.f, 0.f, 0.f);
                *(float4*)&sX[r][q * 4] = val;
            }
        }
        for (int idx = tid; idx < 16 * FOUT; idx += 256)
            *(float4*)&sW[idx * 4] = *(const float4*)&W[(size_t)k0 * FOUT + idx * 4];
        __syncthreads();
        for (int k = 0; k < 64; k += 4) {
            float4 xr[8];
#pragma unroll
            for (int i = 0; i < 8; i++)
                xr[i] = *(const float4*)&sX[r0 + i][k];
#pragma unroll
            for (int kk = 0; kk < 4; kk++) {
                float4 wv = ((const float4*)(sW + (size_t)(k + kk) * FOUT))[cg];
#pragma unroll
                for (int i = 0; i < 8; i++) {
                    float xv = (&xr[i].x)[kk];
                    acc[i][0] = fmaf(xv, wv.x, acc[i][0]);
                    acc[i][1] = fmaf(xv, wv.y, acc[i][1]);
                    acc[i][2] = fmaf(xv, wv.z, acc[i][2]);
                    acc[i][3] = fmaf(xv, wv.w, acc[i][3]);
                }
            }
        }
    }

    // store bf16 Y
#pragma unroll
    for (int i = 0; i < 8; i++) {
        int row = rowbase + r0 + i;
        if (row < N) {
            ushort4 v;
            v.x = f2bf(acc[i][0]); v.y = f2bf(acc[i][1]);
            v.z = f2bf(acc[i][2]); v.w = f2bf(acc[i][3]);
            *(ushort4*)(Ybf + (size_t)row * FOUT + cg * 4) = v;
        }
    }

    // fused att dots
    float4 asv = ((const float4*)attS)[cg];
    float4 adv = ((const float4*)attD)[cg];
    int head = (H == 2) ? (cg >> 4) : 0;
#pragma unroll
    for (int i = 0; i < 8; i++) {
        float ps = acc[i][0] * asv.x + acc[i][1] * asv.y + acc[i][2] * asv.z + acc[i][3] * asv.w;
        float pd = acc[i][0] * adv.x + acc[i][1] * adv.y + acc[i][2] * adv.z + acc[i][3] * adv.w;
#pragma unroll
        for (int o = 1; o <= 8; o <<= 1) { ps += __shfl_xor(ps, o); pd += __shfl_xor(pd, o); }
        int row = rowbase + r0 + i;
        if ((tid & 15) == 0 && row < N) {
            as_[(size_t)row * H + head] = ps;
            ad_[(size_t)row * H + head] = pd;
        }
    }
}

// ---------------- edge-parallel logit precompute ----------------
// eval1: t_h = leakyrelu(as[src].h + ad[dst].h) for H=2; streaming, gathers L2-resident.

__global__ __launch_bounds__(256) void eval1_kernel(const unsigned int* __restrict__ csrc,
                                                    const float* __restrict__ as_,
                                                    const float* __restrict__ ad_,
                                                    float2* __restrict__ ev, int EE) {
    int e = blockIdx.x * 256 + threadIdx.x;
    if (e >= EE) return;
    unsigned int u = csrc[e];
    int s = u & 0xFFFFu, d = u >> 16;
    float2 a = ((const float2*)as_)[s];
    float2 b = ((const float2*)ad_)[d];
    float t0 = a.x + b.x; t0 = t0 > 0.f ? t0 : NEG_SLOPE * t0;
    float t1 = a.y + b.y; t1 = t1 > 0.f ? t1 : NEG_SLOPE * t1;
    ev[e] = make_float2(t0, t1);
}

__global__ __launch_bounds__(256) void eval2_kernel(const unsigned int* __restrict__ csrc,
                                                    const float* __restrict__ as_,
                                                    const float* __restrict__ ad_,
                                                    float* __restrict__ ev, int EE) {
    int e = blockIdx.x * 256 + threadIdx.x;
    if (e >= EE) return;
    unsigned int u = csrc[e];
    float t = as_[u & 0xFFFFu] + ad_[u >> 16];
    ev[e] = t > 0.f ? t : NEG_SLOPE * t;
}

// ---------------- layer-1 softmax+aggregate: one wave per NODE, both heads ----------------
// Logits read contiguously from ev; only xl rows are gathered. Output h1 in bf16 + relu.

__global__ __launch_bounds__(256) void agg1_kernel(const unsigned short* __restrict__ xl,
                                                   const float2* __restrict__ ev,
                                                   const float* __restrict__ bias,
                                                   const int* __restrict__ off,
                                                   const unsigned int* __restrict__ csrc,
                                                   unsigned short* __restrict__ out, int N) {
    __shared__ float4 sps[4][64];   // {p0, p1, as_int(src), -}
    int wiw  = threadIdx.x >> 6;
    int lane = threadIdx.x & 63;
    int node = blockIdx.x * 4 + wiw;
    if (node >= N) return;
    int beg = off[node], end = off[node + 1];
    int deg = end - beg;

    int cl  = lane & 15;
    int sub = lane >> 4;
    int hd1 = (cl >> 3) & 1;
    float acc[8];
#pragma unroll
    for (int i = 0; i < 8; i++) acc[i] = 0.f;
    const uint4* xq = (const uint4*)xl + cl;   // + src*16

    if (deg <= 64) {
        int s = 0;
        float t0 = -1e30f, t1 = -1e30f;
        if (lane < deg) {
            s = (int)(csrc[beg + lane] & 0xFFFFu);
            float2 t = ev[beg + lane];
            t0 = t.x; t1 = t.y;
        }
        float m0 = t0, m1 = t1;
#pragma unroll
        for (int o = 32; o; o >>= 1) {
            m0 = fmaxf(m0, __shfl_xor(m0, o));
            m1 = fmaxf(m1, __shfl_xor(m1, o));
        }
        float e0 = (lane < deg) ? __expf(t0 - m0) : 0.f;
        float e1 = (lane < deg) ? __expf(t1 - m1) : 0.f;
        float s0 = e0, s1 = e1;
#pragma unroll
        for (int o = 32; o; o >>= 1) { s0 += __shfl_xor(s0, o); s1 += __shfl_xor(s1, o); }
        sps[wiw][lane] = make_float4(e0 / s0, e1 / s1, __int_as_float(s), 0.f);
        int iters = (deg + 3) >> 2;
#pragma unroll 8
        for (int j = 0; j < iters; j++) {
            float4 q = sps[wiw][j * 4 + sub];
            float a  = hd1 ? q.y : q.x;
            int   sj = __float_as_int(q.z);
            uint4 v  = xq[(size_t)sj * 16];
            acc[0] = fmaf(a, bf_lo(v.x), acc[0]); acc[1] = fmaf(a, bf_hi(v.x), acc[1]);
            acc[2] = fmaf(a, bf_lo(v.y), acc[2]); acc[3] = fmaf(a, bf_hi(v.y), acc[3]);
            acc[4] = fmaf(a, bf_lo(v.z), acc[4]); acc[5] = fmaf(a, bf_hi(v.z), acc[5]);
            acc[6] = fmaf(a, bf_lo(v.w), acc[6]); acc[7] = fmaf(a, bf_hi(v.w), acc[7]);
        }
    } else {
        // 3-pass fallback (deg > 64)
        float m0 = -1e30f, m1 = -1e30f;
        for (int b = beg; b < end; b += 64) {
            int e = b + lane;
            if (e < end) {
                float2 t = ev[e];
                m0 = fmaxf(m0, t.x); m1 = fmaxf(m1, t.y);
            }
        }
#pragma unroll
        for (int o = 32; o; o >>= 1) {
            m0 = fmaxf(m0, __shfl_xor(m0, o));
            m1 = fmaxf(m1, __shfl_xor(m1, o));
        }
        float s0 = 0.f, s1 = 0.f;
        for (int b = beg; b < end; b += 64) {
            int e = b + lane;
            if (e < end) {
                float2 t = ev[e];
                s0 += __expf(t.x - m0); s1 += __expf(t.y - m1);
            }
        }
#pragma unroll
        for (int o = 32; o; o >>= 1) { s0 += __shfl_xor(s0, o); s1 += __shfl_xor(s1, o); }
        float i0 = 1.f / s0, i1 = 1.f / s1;
        for (int b = beg; b < end; b += 64) {
            int cnt = end - b; if (cnt > 64) cnt = 64;
            float p0 = 0.f, p1 = 0.f; int s = 0;
            if (lane < cnt) {
                s = (int)(csrc[b + lane] & 0xFFFFu);
                float2 t = ev[b + lane];
                p0 = __expf(t.x - m0) * i0; p1 = __expf(t.y - m1) * i1;
            }
            sps[wiw][lane] = make_float4(p0, p1, __int_as_float(s), 0.f);
            int iters = (cnt + 3) >> 2;
#pragma unroll 8
            for (int j = 0; j < iters; j++) {
                float4 q = sps[wiw][j * 4 + sub];
                float a  = hd1 ? q.y : q.x;
                int   sj = __float_as_int(q.z);
                uint4 v  = xq[(size_t)sj * 16];
                acc[0] = fmaf(a, bf_lo(v.x), acc[0]); acc[1] = fmaf(a, bf_hi(v.x), acc[1]);
                acc[2] = fmaf(a, bf_lo(v.y), acc[2]); acc[3] = fmaf(a, bf_hi(v.y), acc[3]);
                acc[4] = fmaf(a, bf_lo(v.z), acc[4]); acc[5] = fmaf(a, bf_hi(v.z), acc[5]);
                acc[6] = fmaf(a, bf_lo(v.w), acc[6]); acc[7] = fmaf(a, bf_hi(v.w), acc[7]);
            }
        }
    }
#pragma unroll
    for (int o = 16; o <= 32; o <<= 1)
#pragma unroll
        for (int i = 0; i < 8; i++) acc[i] += __shfl_xor(acc[i], o);
    if (sub == 0) {
        const float* bp = bias + cl * 8;
        uint4 pk;
        float v0, v1;
        v0 = fmaxf(acc[0] + bp[0], 0.f); v1 = fmaxf(acc[1] + bp[1], 0.f); pk.x = pk2bf(v0, v1);
        v0 = fmaxf(acc[2] + bp[2], 0.f); v1 = fmaxf(acc[3] + bp[3], 0.f); pk.y = pk2bf(v0, v1);
        v0 = fmaxf(acc[4] + bp[4], 0.f); v1 = fmaxf(acc[5] + bp[5], 0.f); pk.z = pk2bf(v0, v1);
        v0 = fmaxf(acc[6] + bp[6], 0.f); v1 = fmaxf(acc[7] + bp[7], 0.f); pk.w = pk2bf(v0, v1);
        *(uint4*)(out + (size_t)node * 128 + cl * 8) = pk;
    }
}

// ---------------- layer-2 softmax+aggregate: one wave per node, H=1, fp32 out ----------------

__global__ __launch_bounds__(256) void agg2_kernel(const unsigned short* __restrict__ xl,
                                                   const float* __restrict__ ev,
                                                   const float* __restrict__ bias,
                                                   const int* __restrict__ off,
                                                   const unsigned int* __restrict__ csrc,
                                                   float* __restrict__ out, int N) {
    __shared__ float2 sps[4][64];   // {p, as_int(src)}
    int wiw  = threadIdx.x >> 6;
    int lane = threadIdx.x & 63;
    int node = blockIdx.x * 4 + wiw;
    if (node >= N) return;
    int beg = off[node], end = off[node + 1];
    int deg = end - beg;

    int cl  = lane & 7;
    int sub = lane >> 3;
    float acc[8];
#pragma unroll
    for (int i = 0; i < 8; i++) acc[i] = 0.f;
    const uint4* xq = (const uint4*)xl + cl;   // + src*8

    if (deg <= 64) {
        int s = 0;
        float t = -1e30f;
        if (lane < deg) {
            s = (int)(csrc[beg + lane] & 0xFFFFu);
            t = ev[beg + lane];
        }
        float m = t;
#pragma unroll
        for (int o = 32; o; o >>= 1) m = fmaxf(m, __shfl_xor(m, o));
        float evv = (lane < deg) ? __expf(t - m) : 0.f;
        float sum = evv;
#pragma unroll
        for (int o = 32; o; o >>= 1) sum += __shfl_xor(sum, o);
        sps[wiw][lane] = make_float2(evv / sum, __int_as_float(s));
        int iters = (deg + 7) >> 3;
#pragma unroll 8
        for (int j = 0; j < iters; j++) {
            float2 q = sps[wiw][j * 8 + sub];
            float a  = q.x;
            int   sj = __float_as_int(q.y);
            uint4 v  = xq[(size_t)sj * 8];
            acc[0] = fmaf(a, bf_lo(v.x), acc[0]); acc[1] = fmaf(a, bf_hi(v.x), acc[1]);
            acc[2] = fmaf(a, bf_lo(v.y), acc[2]); acc[3] = fmaf(a, bf_hi(v.y), acc[3]);
            acc[4] = fmaf(a, bf_lo(v.z), acc[4]); acc[5] = fmaf(a, bf_hi(v.z), acc[5]);
            acc[6] = fmaf(a, bf_lo(v.w), acc[6]); acc[7] = fmaf(a, bf_hi(v.w), acc[7]);
        }
    } else {
        float m = -1e30f;
        for (int b = beg; b < end; b += 64) {
            int e = b + lane;
            if (e < end) m = fmaxf(m, ev[e]);
        }
#pragma unroll
        for (int o = 32; o; o >>= 1) m = fmaxf(m, __shfl_xor(m, o));
        float sum = 0.f;
        for (int b = beg; b < end; b += 64) {
            int e = b + lane;
            if (e < end) sum += __expf(ev[e] - m);
        }
#pragma unroll
        for (int o = 32; o; o >>= 1) sum += __shfl_xor(sum, o);
        float inv = 1.f / sum;
        for (int b = beg; b < end; b += 64) {
            int cnt = end - b; if (cnt > 64) cnt = 64;
            float p = 0.f; int s = 0;
            if (lane < cnt) {
                s = (int)(csrc[b + lane] & 0xFFFFu);
                p = __expf(ev[b + lane] - m) * inv;
            }
            sps[wiw][lane] = make_float2(p, __int_as_float(s));
            int iters = (cnt + 7) >> 3;
#pragma unroll 8
            for (int j = 0; j < iters; j++) {
                float2 q = sps[wiw][j * 8 + sub];
                float a  = q.x;
                int   sj = __float_as_int(q.y);
                uint4 v  = xq[(size_t)sj * 8];
                acc[0] = fmaf(a, bf_lo(v.x), acc[0]); acc[1] = fmaf(a, bf_hi(v.x), acc[1]);
                acc[2] = fmaf(a, bf_lo(v.y), acc[2]); acc[3] = fmaf(a, bf_hi(v.y), acc[3]);
                acc[4] = fmaf(a, bf_lo(v.z), acc[4]); acc[5] = fmaf(a, bf_hi(v.z), acc[5]);
                acc[6] = fmaf(a, bf_lo(v.w), acc[6]); acc[7] = fmaf(a, bf_hi(v.w), acc[7]);
            }
        }
    }
#pragma unroll
    for (int o = 8; o <= 32; o <<= 1)
#pragma unroll
        for (int i = 0; i < 8; i++) acc[i] += __shfl_xor(acc[i], o);
    if (sub == 0) {
        float* op = out + (size_t)node * 64 + cl * 8;
        const float* bp = bias + cl * 8;
#pragma unroll
        for (int i = 0; i < 8; i++) op[i] = fmaxf(acc[i] + bp[i], 0.f);
    }
}

// ---------------- launcher ----------------

extern "C" void kernel_launch(void* const* d_in, const int* in_sizes, int n_in,
                              void* d_out, int out_size, void* d_ws, size_t ws_size,
                              hipStream_t stream) {
    const float* x        = (const float*)d_in[0];
    const int*   ei       = (const int*)d_in[1];   // int32 per harness convention
    const float* W1       = (const float*)d_in[2];
    const float* attS1    = (const float*)d_in[3];
    const float* attD1    = (const float*)d_in[4];
    const float* b1       = (const float*)d_in[5];
    const float* W2       = (const float*)d_in[6];
    const float* attS2    = (const float*)d_in[7];
    const float* attD2    = (const float*)d_in[8];
    const float* b2       = (const float*)d_in[9];
    float* out            = (float*)d_out;

    int N  = in_sizes[0] / 128;
    int E  = in_sizes[1] / 2;
    int EE = E + N;                    // with self-loops
    int K  = (N + NB - 1) >> LOG_NB;   // buckets (98 for N=50000)

    char* w = (char*)d_ws;
    auto alloc = [&](size_t bytes) -> void* {
        void* p = (void*)w;
        w += (bytes + 255) & ~(size_t)255;
        return p;
    };
    int*   bcnt = (int*)alloc((size_t)(K + 1) * 4);
    int*   boff = (int*)alloc((size_t)(K + 1) * 4);
    int*   bcur = (int*)alloc((size_t)(K + 1) * 4);
    int*   off  = (int*)alloc((size_t)(N + 1) * 4);
    unsigned int* csrc = (unsigned int*)alloc((size_t)EE * 4);
    unsigned short* xl1 = (unsigned short*)alloc((size_t)N * 128 * 2);  // bf16; aliases bkt, xl2
    float* sd1  = (float*)alloc((size_t)N * 2 * 4);
    float* dd1  = (float*)alloc((size_t)N * 2 * 4);
    unsigned short* h1 = (unsigned short*)alloc((size_t)N * 128 * 2);   // bf16
    float2* ev1 = (float2*)alloc((size_t)EE * 8);                        // aliases ev2

    unsigned int* bkt = (unsigned int*)xl1;  // 6.4MB < 12.8MB; dead before gemm writes xl1
    unsigned short* xl2 = xl1;               // layer-2 xl (bf16), xl1 dead by then
    float* sd2 = sd1;
    float* dd2 = dd1;
    float* ev2 = (float*)ev1;                // ev1 dead after agg1

    hipMemsetAsync(bcnt, 0, (size_t)(K + 1) * 4, stream);

    int G  = 256;
    int CH = (E + G - 1) / G;
    int GE = (EE + 255) / 256;
    sort_count_kernel<<<G, 256, 0, stream>>>(ei, E, K, CH, bcnt);
    sort_scan_kernel<<<1, MAXK, 0, stream>>>(bcnt, boff, bcur, K, E);
    sort_scatter_kernel<<<G, 256, 0, stream>>>(ei, E, K, CH, bcur, bkt);
    sort_finalize_kernel<<<K, 256, 0, stream>>>(bkt, boff, off, csrc, N);

    // ---- layer 1: H=2, C=64 ----
    gemm_att_kernel<128, 2, false><<<(N + 63) / 64, 256, 0, stream>>>(x, W1, attS1, attD1, xl1, sd1, dd1, N);
    eval1_kernel<<<GE, 256, 0, stream>>>(csrc, sd1, dd1, ev1, EE);
    agg1_kernel<<<(N + 3) / 4, 256, 0, stream>>>(xl1, ev1, b1, off, csrc, h1, N);

    // ---- layer 2: H=1, C=64 ----
    gemm_att_kernel<64, 1, true><<<(N + 127) / 128, 256, 0, stream>>>(h1, W2, attS2, attD2, xl2, sd2, dd2, N);
    eval2_kernel<<<GE, 256, 0, stream>>>(csrc, sd2, dd2, ev2, EE);
    agg2_kernel<<<(N + 3) / 4, 256, 0, stream>>>(xl2, ev2, b2, off, csrc, out, N);
}

// Round 11
// 341.261 us; speedup vs baseline: 1.0454x; 1.0454x over previous
//
#include <hip/hip_runtime.h>
#include <cstdint>
#include <cstddef>

#define NEG_SLOPE 0.2f

// Edge packing relies on N <= 65536 (here N = 50000): edge = src | (dst<<16).
// Self-loops are NOT sorted: placed analytically (one per node, first slot).
// csrc[] stores the PACKED edge (src in low 16, dst in high 16).
#define NB 512        // nodes per bucket
#define LOG_NB 9
#define MAXK 512

__device__ inline unsigned short f2bf(float f) {          // RNE fp32->bf16
    unsigned int u = __float_as_uint(f);
    u += 0x7FFFu + ((u >> 16) & 1u);
    return (unsigned short)(u >> 16);
}
__device__ inline float bf_lo(unsigned int u) { return __uint_as_float(u << 16); }
__device__ inline float bf_hi(unsigned int u) { return __uint_as_float(u & 0xFFFF0000u); }
__device__ inline unsigned int pk2bf(float lo, float hi) {
    return (unsigned int)f2bf(lo) | ((unsigned int)f2bf(hi) << 16);
}

// ---------------- P1: per-block bucket histogram (real edges only) ----------------
__global__ __launch_bounds__(256) void sort_count_kernel(const int* __restrict__ ei, int E,
                                                         int K, int CH, int* __restrict__ bcnt) {
    __shared__ int hist[MAXK];
    int tid = threadIdx.x;
    for (int i = tid; i < K; i += 256) hist[i] = 0;
    __syncthreads();
    int lo = blockIdx.x * CH;
    int hi = lo + CH; if (hi > E) hi = E;
    for (int e = lo + tid; e < hi; e += 256)
        atomicAdd(&hist[ei[(size_t)E + e] >> LOG_NB], 1);
    __syncthreads();
    for (int i = tid; i < K; i += 256)
        if (hist[i]) atomicAdd(&bcnt[i], hist[i]);
}

// ---------------- P2: scan bucket counts ----------------
__global__ void sort_scan_kernel(const int* __restrict__ bcnt, int* __restrict__ boff,
                                 int* __restrict__ bcur, int K, int E) {
    __shared__ int buf[MAXK];
    int tid = threadIdx.x;   // 512 threads
    int v = (tid < K) ? bcnt[tid] : 0;
    buf[tid] = v;
    __syncthreads();
    for (int o = 1; o < MAXK; o <<= 1) {
        int t = (tid >= o) ? buf[tid - o] : 0;
        __syncthreads();
        buf[tid] += t;
        __syncthreads();
    }
    if (tid < K) {
        int ex = buf[tid] - v;
        boff[tid] = ex;
        bcur[tid] = ex;
    }
    if (tid == K) boff[K] = E;
}

// ---------------- P3: scatter packed real edges into buckets ----------------
__global__ __launch_bounds__(256) void sort_scatter_kernel(const int* __restrict__ ei, int E,
                                                           int K, int CH, int* __restrict__ bcur,
                                                           unsigned int* __restrict__ bkt) {
    __shared__ int hist[MAXK];
    __shared__ int base[MAXK];
    int tid = threadIdx.x;
    for (int i = tid; i < K; i += 256) hist[i] = 0;
    __syncthreads();
    int lo = blockIdx.x * CH;
    int hi = lo + CH; if (hi > E) hi = E;
    for (int e = lo + tid; e < hi; e += 256)
        atomicAdd(&hist[ei[(size_t)E + e] >> LOG_NB], 1);
    __syncthreads();
    for (int i = tid; i < K; i += 256) {
        int c = hist[i];
        base[i] = c ? atomicAdd(&bcur[i], c) : 0;
    }
    __syncthreads();
    for (int i = tid; i < K; i += 256) hist[i] = 0;
    __syncthreads();
    for (int e = lo + tid; e < hi; e += 256) {
        int s = ei[e];
        int d = ei[(size_t)E + e];
        int k = d >> LOG_NB;
        int r = atomicAdd(&hist[k], 1);
        bkt[(size_t)base[k] + r] = (unsigned int)s | ((unsigned int)d << 16);
    }
}

// ---------------- P4: per-bucket CSR finalize (parallel prefix; +1 self slot per node) ----------------
__global__ __launch_bounds__(256) void sort_finalize_kernel(const unsigned int* __restrict__ bkt,
                                                            const int* __restrict__ boff,
                                                            int* __restrict__ off,
                                                            unsigned int* __restrict__ csrc, int N) {
    __shared__ int nhist[NB];
    __shared__ int part[256];
    __shared__ int loff[NB];
    int k = blockIdx.x;
    int tid = threadIdx.x;
    int node0 = k << LOG_NB;
    int nh = N - node0; if (nh > NB) nh = NB;
    int beg = boff[k], end = boff[k + 1];
    for (int i = tid; i < NB; i += 256) nhist[i] = 0;
    __syncthreads();
    for (int e = beg + tid; e < end; e += 256)
        atomicAdd(&nhist[(bkt[e] >> 16) - node0], 1);
    __syncthreads();
    int i0 = 2 * tid, i1 = 2 * tid + 1;
    int v0 = (i0 < nh) ? nhist[i0] + 1 : 0;
    int v1 = (i1 < nh) ? nhist[i1] + 1 : 0;
    part[tid] = v0 + v1;
    __syncthreads();
    for (int o = 1; o < 256; o <<= 1) {
        int t = (tid >= o) ? part[tid - o] : 0;
        __syncthreads();
        part[tid] += t;
        __syncthreads();
    }
    int gbase = beg + node0;   // node0 self slots precede this bucket
    int base = gbase + ((tid > 0) ? part[tid - 1] : 0);
    if (i0 < nh) loff[i0] = base;
    if (i1 < nh) loff[i1] = base + v0;
    __syncthreads();
    for (int i = tid; i < nh; i += 256) {
        int node = node0 + i;
        off[node] = loff[i];
        csrc[loff[i]] = (unsigned int)node | ((unsigned int)node << 16);  // self-loop first
        nhist[i] = loff[i] + 1;
    }
    if (node0 + nh == N && tid == 0) off[N] = gbase + part[255];
    __syncthreads();
    for (int e = beg + tid; e < end; e += 256) {
        unsigned int p = bkt[e];
        int pos = atomicAdd(&nhist[(p >> 16) - node0], 1);
        csrc[pos] = p;   // keep packed (src | dst<<16)
    }
}

// ---- GEMM + fused att dots, register-tiled 8 rows x 4 cols per thread ----
// BF16IN: input matrix is bf16 (layer 2 reads h1 in bf16).

template <int FOUT, int H, bool BF16IN>
__global__ __launch_bounds__(256) void gemm_att_kernel(const void* __restrict__ Xv,
                                                       const float* __restrict__ W,
                                                       const float* __restrict__ attS,
                                                       const float* __restrict__ attD,
                                                       unsigned short* __restrict__ Ybf,
                                                       float* __restrict__ as_,
                                                       float* __restrict__ ad_, int N) {
    constexpr int ROWS = 8192 / FOUT;   // 64 (F=128) or 128 (F=64)
    constexpr int CG   = FOUT / 4;
    __shared__ float sX[ROWS][68];      // +4 pad keeps rows 16B-aligned
    __shared__ float sW[64 * FOUT];
    int tid = threadIdx.x;
    int rowbase = blockIdx.x * ROWS;
    int cg = tid % CG;
    int rg = tid / CG;
    int r0 = rg * 8;

    float acc[8][4];
#pragma unroll
    for (int i = 0; i < 8; i++)
#pragma unroll
        for (int c = 0; c < 4; c++) acc[i][c] = 0.f;

    for (int k0 = 0; k0 < 128; k0 += 64) {
        __syncthreads();
        if (BF16IN) {
            const unsigned short* Xb = (const unsigned short*)Xv;
            for (int idx = tid; idx < ROWS * 8; idx += 256) {
                int r = idx >> 3, g = idx & 7;
                int row = rowbase + r;
                uint4 v = (row < N) ? *(const uint4*)&Xb[(size_t)row * 128 + k0 + g * 8]
                                    : make_uint4(0, 0, 0, 0);
                float* dst = &sX[r][g * 8];
                dst[0] = bf_lo(v.x); dst[1] = bf_hi(v.x);
                dst[2] = bf_lo(v.y); dst[3] = bf_hi(v.y);
                dst[4] = bf_lo(v.z); dst[5] = bf_hi(v.z);
                dst[6] = bf_lo(v.w); dst[7] = bf_hi(v.w);
            }
        } else {
            const float* X = (const float*)Xv;
            for (int idx = tid; idx < ROWS * 16; idx += 256) {
                int r = idx >> 4, q = idx & 15;
                int row = rowbase + r;
                float4 val = (row < N) ? *(const float4*)&X[(size_t)row * 128 + k0 + q * 4]
                                       : make_float4(0.f, 0.f, 0.f, 0.f);
                *(float4*)&sX[r][q * 4] = val;
            }
        }
        for (int idx = tid; idx < 16 * FOUT; idx += 256)
            *(float4*)&sW[idx * 4] = *(const float4*)&W[(size_t)k0 * FOUT + idx * 4];
        __syncthreads();
        for (int k = 0; k < 64; k += 4) {
            float4 xr[8];
#pragma unroll
            for (int i = 0; i < 8; i++)
                xr[i] = *(const float4*)&sX[r0 + i][k];
#pragma unroll
            for (int kk = 0; kk < 4; kk++) {
                float4 wv = ((const float4*)(sW + (size_t)(k + kk) * FOUT))[cg];
#pragma unroll
                for (int i = 0; i < 8; i++) {
                    float xv = (&xr[i].x)[kk];
                    acc[i][0] = fmaf(xv, wv.x, acc[i][0]);
                    acc[i][1] = fmaf(xv, wv.y, acc[i][1]);
                    acc[i][2] = fmaf(xv, wv.z, acc[i][2]);
                    acc[i][3] = fmaf(xv, wv.w, acc[i][3]);
                }
            }
        }
    }

    // store bf16 Y
#pragma unroll
    for (int i = 0; i < 8; i++) {
        int row = rowbase + r0 + i;
        if (row < N) {
            ushort4 v;
            v.x = f2bf(acc[i][0]); v.y = f2bf(acc[i][1]);
            v.z = f2bf(acc[i][2]); v.w = f2bf(acc[i][3]);
            *(ushort4*)(Ybf + (size_t)row * FOUT + cg * 4) = v;
        }
    }

    // fused att dots
    float4 asv = ((const float4*)attS)[cg];
    float4 adv = ((const float4*)attD)[cg];
    int head = (H == 2) ? (cg >> 4) : 0;
#pragma unroll
    for (int i = 0; i < 8; i++) {
        float ps = acc[i][0] * asv.x + acc[i][1] * asv.y + acc[i][2] * asv.z + acc[i][3] * asv.w;
        float pd = acc[i][0] * adv.x + acc[i][1] * adv.y + acc[i][2] * adv.z + acc[i][3] * adv.w;
#pragma unroll
        for (int o = 1; o <= 8; o <<= 1) { ps += __shfl_xor(ps, o); pd += __shfl_xor(pd, o); }
        int row = rowbase + r0 + i;
        if ((tid & 15) == 0 && row < N) {
            as_[(size_t)row * H + head] = ps;
            ad_[(size_t)row * H + head] = pd;
        }
    }
}

// ---------------- layer-1 softmax+aggregate: one wave per NODE, both heads ----------------
// Inline logits (as_ is L2-resident); gather loop uses 32-bit byte offsets.

__global__ __launch_bounds__(256) void agg1_kernel(const unsigned short* __restrict__ xl,
                                                   const float* __restrict__ as_,
                                                   const float* __restrict__ ad_,
                                                   const float* __restrict__ bias,
                                                   const int* __restrict__ off,
                                                   const unsigned int* __restrict__ csrc,
                                                   unsigned short* __restrict__ out, int N) {
    __shared__ float4 sps[4][64];   // {p0, p1, as_int(byteoff), -}
    int wiw  = threadIdx.x >> 6;
    int lane = threadIdx.x & 63;
    int node = blockIdx.x * 4 + wiw;
    if (node >= N) return;
    int beg = off[node], end = off[node + 1];
    int deg = end - beg;
    float2 adn = ((const float2*)ad_)[node];

    int cl  = lane & 15;
    int sub = lane >> 4;
    int hd1 = (cl >> 3) & 1;
    float acc[8];
#pragma unroll
    for (int i = 0; i < 8; i++) acc[i] = 0.f;
    const char* xbase = (const char*)xl + cl * 16;   // + src*256

    if (deg <= 64) {
        int so = 0;
        float t0 = -1e30f, t1 = -1e30f;
        if (lane < deg) {
            int s = (int)(csrc[beg + lane] & 0xFFFFu);
            so = s << 8;                       // byte offset of row
            float2 asv = ((const float2*)as_)[s];
            t0 = asv.x + adn.x; t0 = t0 > 0.f ? t0 : NEG_SLOPE * t0;
            t1 = asv.y + adn.y; t1 = t1 > 0.f ? t1 : NEG_SLOPE * t1;
        }
        float m0 = t0, m1 = t1;
#pragma unroll
        for (int o = 32; o; o >>= 1) {
            m0 = fmaxf(m0, __shfl_xor(m0, o));
            m1 = fmaxf(m1, __shfl_xor(m1, o));
        }
        float e0 = (lane < deg) ? __expf(t0 - m0) : 0.f;
        float e1 = (lane < deg) ? __expf(t1 - m1) : 0.f;
        float s0 = e0, s1 = e1;
#pragma unroll
        for (int o = 32; o; o >>= 1) { s0 += __shfl_xor(s0, o); s1 += __shfl_xor(s1, o); }
        sps[wiw][lane] = make_float4(e0 / s0, e1 / s1, __int_as_float(so), 0.f);
        int iters = (deg + 3) >> 2;
#pragma unroll 8
        for (int j = 0; j < iters; j++) {
            float4 q = sps[wiw][j * 4 + sub];
            float a  = hd1 ? q.y : q.x;
            uint4 v  = *(const uint4*)(xbase + __float_as_int(q.z));
            acc[0] = fmaf(a, bf_lo(v.x), acc[0]); acc[1] = fmaf(a, bf_hi(v.x), acc[1]);
            acc[2] = fmaf(a, bf_lo(v.y), acc[2]); acc[3] = fmaf(a, bf_hi(v.y), acc[3]);
            acc[4] = fmaf(a, bf_lo(v.z), acc[4]); acc[5] = fmaf(a, bf_hi(v.z), acc[5]);
            acc[6] = fmaf(a, bf_lo(v.w), acc[6]); acc[7] = fmaf(a, bf_hi(v.w), acc[7]);
        }
    } else {
        // 3-pass fallback (deg > 64)
        float m0 = -1e30f, m1 = -1e30f;
        for (int b = beg; b < end; b += 64) {
            int e = b + lane;
            if (e < end) {
                int s = (int)(csrc[e] & 0xFFFFu);
                float2 asv = ((const float2*)as_)[s];
                float t0 = asv.x + adn.x; t0 = t0 > 0.f ? t0 : NEG_SLOPE * t0;
                float t1 = asv.y + adn.y; t1 = t1 > 0.f ? t1 : NEG_SLOPE * t1;
                m0 = fmaxf(m0, t0); m1 = fmaxf(m1, t1);
            }
        }
#pragma unroll
        for (int o = 32; o; o >>= 1) {
            m0 = fmaxf(m0, __shfl_xor(m0, o));
            m1 = fmaxf(m1, __shfl_xor(m1, o));
        }
        float s0 = 0.f, s1 = 0.f;
        for (int b = beg; b < end; b += 64) {
            int e = b + lane;
            if (e < end) {
                int s = (int)(csrc[e] & 0xFFFFu);
                float2 asv = ((const float2*)as_)[s];
                float t0 = asv.x + adn.x; t0 = t0 > 0.f ? t0 : NEG_SLOPE * t0;
                float t1 = asv.y + adn.y; t1 = t1 > 0.f ? t1 : NEG_SLOPE * t1;
                s0 += __expf(t0 - m0); s1 += __expf(t1 - m1);
            }
        }
#pragma unroll
        for (int o = 32; o; o >>= 1) { s0 += __shfl_xor(s0, o); s1 += __shfl_xor(s1, o); }
        float i0 = 1.f / s0, i1 = 1.f / s1;
        for (int b = beg; b < end; b += 64) {
            int cnt = end - b; if (cnt > 64) cnt = 64;
            float p0 = 0.f, p1 = 0.f; int so = 0;
            if (lane < cnt) {
                int s = (int)(csrc[b + lane] & 0xFFFFu);
                so = s << 8;
                float2 asv = ((const float2*)as_)[s];
                float t0 = asv.x + adn.x; t0 = t0 > 0.f ? t0 : NEG_SLOPE * t0;
                float t1 = asv.y + adn.y; t1 = t1 > 0.f ? t1 : NEG_SLOPE * t1;
                p0 = __expf(t0 - m0) * i0; p1 = __expf(t1 - m1) * i1;
            }
            sps[wiw][lane] = make_float4(p0, p1, __int_as_float(so), 0.f);
            int iters = (cnt + 3) >> 2;
#pragma unroll 8
            for (int j = 0; j < iters; j++) {
                float4 q = sps[wiw][j * 4 + sub];
                float a  = hd1 ? q.y : q.x;
                uint4 v  = *(const uint4*)(xbase + __float_as_int(q.z));
                acc[0] = fmaf(a, bf_lo(v.x), acc[0]); acc[1] = fmaf(a, bf_hi(v.x), acc[1]);
                acc[2] = fmaf(a, bf_lo(v.y), acc[2]); acc[3] = fmaf(a, bf_hi(v.y), acc[3]);
                acc[4] = fmaf(a, bf_lo(v.z), acc[4]); acc[5] = fmaf(a, bf_hi(v.z), acc[5]);
                acc[6] = fmaf(a, bf_lo(v.w), acc[6]); acc[7] = fmaf(a, bf_hi(v.w), acc[7]);
            }
        }
    }
#pragma unroll
    for (int o = 16; o <= 32; o <<= 1)
#pragma unroll
        for (int i = 0; i < 8; i++) acc[i] += __shfl_xor(acc[i], o);
    if (sub == 0) {
        const float* bp = bias + cl * 8;
        uint4 pk;
        float v0, v1;
        v0 = fmaxf(acc[0] + bp[0], 0.f); v1 = fmaxf(acc[1] + bp[1], 0.f); pk.x = pk2bf(v0, v1);
        v0 = fmaxf(acc[2] + bp[2], 0.f); v1 = fmaxf(acc[3] + bp[3], 0.f); pk.y = pk2bf(v0, v1);
        v0 = fmaxf(acc[4] + bp[4], 0.f); v1 = fmaxf(acc[5] + bp[5], 0.f); pk.z = pk2bf(v0, v1);
        v0 = fmaxf(acc[6] + bp[6], 0.f); v1 = fmaxf(acc[7] + bp[7], 0.f); pk.w = pk2bf(v0, v1);
        *(uint4*)(out + (size_t)node * 128 + cl * 8) = pk;
    }
}

// ---------------- layer-2 softmax+aggregate: one wave per node, H=1, fp32 out ----------------

__global__ __launch_bounds__(256) void agg2_kernel(const unsigned short* __restrict__ xl,
                                                   const float* __restrict__ as_,
                                                   const float* __restrict__ ad_,
                                                   const float* __restrict__ bias,
                                                   const int* __restrict__ off,
                                                   const unsigned int* __restrict__ csrc,
                                                   float* __restrict__ out, int N) {
    __shared__ float2 sps[4][64];   // {p, as_int(byteoff)}
    int wiw  = threadIdx.x >> 6;
    int lane = threadIdx.x & 63;
    int node = blockIdx.x * 4 + wiw;
    if (node >= N) return;
    int beg = off[node], end = off[node + 1];
    int deg = end - beg;
    float adn = ad_[node];

    int cl  = lane & 7;
    int sub = lane >> 3;
    float acc[8];
#pragma unroll
    for (int i = 0; i < 8; i++) acc[i] = 0.f;
    const char* xbase = (const char*)xl + cl * 16;   // + src*128

    if (deg <= 64) {
        int so = 0;
        float t = -1e30f;
        if (lane < deg) {
            int s = (int)(csrc[beg + lane] & 0xFFFFu);
            so = s << 7;
            t = as_[s] + adn;
            t = t > 0.f ? t : NEG_SLOPE * t;
        }
        float m = t;
#pragma unroll
        for (int o = 32; o; o >>= 1) m = fmaxf(m, __shfl_xor(m, o));
        float evv = (lane < deg) ? __expf(t - m) : 0.f;
        float sum = evv;
#pragma unroll
        for (int o = 32; o; o >>= 1) sum += __shfl_xor(sum, o);
        sps[wiw][lane] = make_float2(evv / sum, __int_as_float(so));
        int iters = (deg + 7) >> 3;
#pragma unroll 8
        for (int j = 0; j < iters; j++) {
            float2 q = sps[wiw][j * 8 + sub];
            float a  = q.x;
            uint4 v  = *(const uint4*)(xbase + __float_as_int(q.y));
            acc[0] = fmaf(a, bf_lo(v.x), acc[0]); acc[1] = fmaf(a, bf_hi(v.x), acc[1]);
            acc[2] = fmaf(a, bf_lo(v.y), acc[2]); acc[3] = fmaf(a, bf_hi(v.y), acc[3]);
            acc[4] = fmaf(a, bf_lo(v.z), acc[4]); acc[5] = fmaf(a, bf_hi(v.z), acc[5]);
            acc[6] = fmaf(a, bf_lo(v.w), acc[6]); acc[7] = fmaf(a, bf_hi(v.w), acc[7]);
        }
    } else {
        float m = -1e30f;
        for (int b = beg; b < end; b += 64) {
            int e = b + lane;
            if (e < end) {
                float t = as_[csrc[e] & 0xFFFFu] + adn;
                t = t > 0.f ? t : NEG_SLOPE * t;
                m = fmaxf(m, t);
            }
        }
#pragma unroll
        for (int o = 32; o; o >>= 1) m = fmaxf(m, __shfl_xor(m, o));
        float sum = 0.f;
        for (int b = beg; b < end; b += 64) {
            int e = b + lane;
            if (e < end) {
                float t = as_[csrc[e] & 0xFFFFu] + adn;
                t = t > 0.f ? t : NEG_SLOPE * t;
                sum += __expf(t - m);
            }
        }
#pragma unroll
        for (int o = 32; o; o >>= 1) sum += __shfl_xor(sum, o);
        float inv = 1.f / sum;
        for (int b = beg; b < end; b += 64) {
            int cnt = end - b; if (cnt > 64) cnt = 64;
            float p = 0.f; int so = 0;
            if (lane < cnt) {
                int s = (int)(csrc[b + lane] & 0xFFFFu);
                so = s << 7;
                float t = as_[s] + adn;
                t = t > 0.f ? t : NEG_SLOPE * t;
                p = __expf(t - m) * inv;
            }
            sps[wiw][lane] = make_float2(p, __int_as_float(so));
            int iters = (cnt + 7) >> 3;
#pragma unroll 8
            for (int j = 0; j < iters; j++) {
                float2 q = sps[wiw][j * 8 + sub];
                float a  = q.x;
                uint4 v  = *(const uint4*)(xbase + __float_as_int(q.y));
                acc[0] = fmaf(a, bf_lo(v.x), acc[0]); acc[1] = fmaf(a, bf_hi(v.x), acc[1]);
                acc[2] = fmaf(a, bf_lo(v.y), acc[2]); acc[3] = fmaf(a, bf_hi(v.y), acc[3]);
                acc[4] = fmaf(a, bf_lo(v.z), acc[4]); acc[5] = fmaf(a, bf_hi(v.z), acc[5]);
                acc[6] = fmaf(a, bf_lo(v.w), acc[6]); acc[7] = fmaf(a, bf_hi(v.w), acc[7]);
            }
        }
    }
#pragma unroll
    for (int o = 8; o <= 32; o <<= 1)
#pragma unroll
        for (int i = 0; i < 8; i++) acc[i] += __shfl_xor(acc[i], o);
    if (sub == 0) {
        float* op = out + (size_t)node * 64 + cl * 8;
        const float* bp = bias + cl * 8;
#pragma unroll
        for (int i = 0; i < 8; i++) op[i] = fmaxf(acc[i] + bp[i], 0.f);
    }
}

// ---------------- launcher ----------------

extern "C" void kernel_launch(void* const* d_in, const int* in_sizes, int n_in,
                              void* d_out, int out_size, void* d_ws, size_t ws_size,
                              hipStream_t stream) {
    const float* x        = (const float*)d_in[0];
    const int*   ei       = (const int*)d_in[1];   // int32 per harness convention
    const float* W1       = (const float*)d_in[2];
    const float* attS1    = (const float*)d_in[3];
    const float* attD1    = (const float*)d_in[4];
    const float* b1       = (const float*)d_in[5];
    const float* W2       = (const float*)d_in[6];
    const float* attS2    = (const float*)d_in[7];
    const float* attD2    = (const float*)d_in[8];
    const float* b2       = (const float*)d_in[9];
    float* out            = (float*)d_out;

    int N  = in_sizes[0] / 128;
    int E  = in_sizes[1] / 2;
    int EE = E + N;                    // with self-loops
    int K  = (N + NB - 1) >> LOG_NB;   // buckets (98 for N=50000)

    char* w = (char*)d_ws;
    auto alloc = [&](size_t bytes) -> void* {
        void* p = (void*)w;
        w += (bytes + 255) & ~(size_t)255;
        return p;
    };
    int*   bcnt = (int*)alloc((size_t)(K + 1) * 4);
    int*   boff = (int*)alloc((size_t)(K + 1) * 4);
    int*   bcur = (int*)alloc((size_t)(K + 1) * 4);
    int*   off  = (int*)alloc((size_t)(N + 1) * 4);
    unsigned int* csrc = (unsigned int*)alloc((size_t)EE * 4);
    unsigned short* xl1 = (unsigned short*)alloc((size_t)N * 128 * 2);  // bf16; aliases bkt, xl2
    float* sd1  = (float*)alloc((size_t)N * 2 * 4);
    float* dd1  = (float*)alloc((size_t)N * 2 * 4);
    unsigned short* h1 = (unsigned short*)alloc((size_t)N * 128 * 2);   // bf16

    unsigned int* bkt = (unsigned int*)xl1;  // 6.4MB < 12.8MB; dead before gemm writes xl1
    unsigned short* xl2 = xl1;               // layer-2 xl (bf16), xl1 dead by then
    float* sd2 = sd1;
    float* dd2 = dd1;

    hipMemsetAsync(bcnt, 0, (size_t)(K + 1) * 4, stream);

    int G  = 256;
    int CH = (E + G - 1) / G;
    sort_count_kernel<<<G, 256, 0, stream>>>(ei, E, K, CH, bcnt);
    sort_scan_kernel<<<1, MAXK, 0, stream>>>(bcnt, boff, bcur, K, E);
    sort_scatter_kernel<<<G, 256, 0, stream>>>(ei, E, K, CH, bcur, bkt);
    sort_finalize_kernel<<<K, 256, 0, stream>>>(bkt, boff, off, csrc, N);

    // ---- layer 1: H=2, C=64 ----
    gemm_att_kernel<128, 2, false><<<(N + 63) / 64, 256, 0, stream>>>(x, W1, attS1, attD1, xl1, sd1, dd1, N);
    agg1_kernel<<<(N + 3) / 4, 256, 0, stream>>>(xl1, sd1, dd1, b1, off, csrc, h1, N);

    // ---- layer 2: H=1, C=64 ----
    gemm_att_kernel<64, 1, true><<<(N + 127) / 128, 256, 0, stream>>>(h1, W2, attS2, attD2, xl2, sd2, dd2, N);
    agg2_kernel<<<(N + 3) / 4, 256, 0, stream>>>(xl2, sd2, dd2, b2, off, csrc, out, N);
}

// Round 13
// 326.923 us; speedup vs baseline: 1.0913x; 1.0439x over previous
//
#include <hip/hip_runtime.h>
#include <cstdint>
#include <cstddef>

#define NEG_SLOPE 0.2f

// Edge packing relies on N <= 65536 (here N = 50000): edge = src | (dst<<16).
// Self-loops are NOT sorted: placed analytically (one per node, first slot).
// csrc[] stores the PACKED edge (src in low 16, dst in high 16).
// NOTE: bkt MUST NOT alias xl1 — scatter and gemm1 run concurrently (fused kernel).
#define NB 512        // nodes per bucket
#define LOG_NB 9
#define MAXK 512

__device__ inline unsigned short f2bf(float f) {          // RNE fp32->bf16
    unsigned int u = __float_as_uint(f);
    u += 0x7FFFu + ((u >> 16) & 1u);
    return (unsigned short)(u >> 16);
}
__device__ inline float bf_lo(unsigned int u) { return __uint_as_float(u << 16); }
__device__ inline float bf_hi(unsigned int u) { return __uint_as_float(u & 0xFFFF0000u); }

// ---------------- P1: per-block bucket histogram (real edges only) ----------------
__global__ __launch_bounds__(256) void sort_count_kernel(const int* __restrict__ ei, int E,
                                                         int K, int CH, int* __restrict__ bcnt) {
    __shared__ int hist[MAXK];
    int tid = threadIdx.x;
    for (int i = tid; i < K; i += 256) hist[i] = 0;
    __syncthreads();
    int lo = blockIdx.x * CH;
    int hi = lo + CH; if (hi > E) hi = E;
    for (int e = lo + tid; e < hi; e += 256)
        atomicAdd(&hist[ei[(size_t)E + e] >> LOG_NB], 1);
    __syncthreads();
    for (int i = tid; i < K; i += 256)
        if (hist[i]) atomicAdd(&bcnt[i], hist[i]);
}

// ---------------- P2: scan bucket counts ----------------
__global__ void sort_scan_kernel(const int* __restrict__ bcnt, int* __restrict__ boff,
                                 int* __restrict__ bcur, int K, int E) {
    __shared__ int buf[MAXK];
    int tid = threadIdx.x;   // 512 threads
    int v = (tid < K) ? bcnt[tid] : 0;
    buf[tid] = v;
    __syncthreads();
    for (int o = 1; o < MAXK; o <<= 1) {
        int t = (tid >= o) ? buf[tid - o] : 0;
        __syncthreads();
        buf[tid] += t;
        __syncthreads();
    }
    if (tid < K) {
        int ex = buf[tid] - v;
        boff[tid] = ex;
        bcur[tid] = ex;
    }
    if (tid == K) boff[K] = E;
}

// ---- GEMM + fused att dots body, register-tiled 8 rows x 4 cols per thread ----

template <int FOUT, int H>
__device__ __forceinline__ void gemm_att_body(const float* __restrict__ X,
                                              const float* __restrict__ W,
                                              const float* __restrict__ attS,
                                              const float* __restrict__ attD,
                                              unsigned short* __restrict__ Ybf,
                                              float* __restrict__ as_,
                                              float* __restrict__ ad_, int N, int bid,
                                              float* sX, float* sW) {
    constexpr int ROWS = 8192 / FOUT;   // 64 (F=128) or 128 (F=64)
    constexpr int CG   = FOUT / 4;
    constexpr int LDX  = 68;            // padded row
    int tid = threadIdx.x;
    int rowbase = bid * ROWS;
    int cg = tid % CG;
    int rg = tid / CG;
    int r0 = rg * 8;

    float acc[8][4];
#pragma unroll
    for (int i = 0; i < 8; i++)
#pragma unroll
        for (int c = 0; c < 4; c++) acc[i][c] = 0.f;

    for (int k0 = 0; k0 < 128; k0 += 64) {
        __syncthreads();
        for (int idx = tid; idx < ROWS * 16; idx += 256) {
            int r = idx >> 4, q = idx & 15;
            int row = rowbase + r;
            float4 val = (row < N) ? *(const float4*)&X[(size_t)row * 128 + k0 + q * 4]
                                   : make_float4(0.f, 0.f, 0.f, 0.f);
            *(float4*)&sX[r * LDX + q * 4] = val;
        }
        for (int idx = tid; idx < 16 * FOUT; idx += 256)
            *(float4*)&sW[idx * 4] = *(const float4*)&W[(size_t)k0 * FOUT + idx * 4];
        __syncthreads();
        for (int k = 0; k < 64; k += 4) {
            float4 xr[8];
#pragma unroll
            for (int i = 0; i < 8; i++)
                xr[i] = *(const float4*)&sX[(r0 + i) * LDX + k];
#pragma unroll
            for (int kk = 0; kk < 4; kk++) {
                float4 wv = ((const float4*)(sW + (size_t)(k + kk) * FOUT))[cg];
#pragma unroll
                for (int i = 0; i < 8; i++) {
                    float xv = (&xr[i].x)[kk];
                    acc[i][0] = fmaf(xv, wv.x, acc[i][0]);
                    acc[i][1] = fmaf(xv, wv.y, acc[i][1]);
                    acc[i][2] = fmaf(xv, wv.z, acc[i][2]);
                    acc[i][3] = fmaf(xv, wv.w, acc[i][3]);
                }
            }
        }
    }

    // store bf16 Y
#pragma unroll
    for (int i = 0; i < 8; i++) {
        int row = rowbase + r0 + i;
        if (row < N) {
            ushort4 v;
            v.x = f2bf(acc[i][0]); v.y = f2bf(acc[i][1]);
            v.z = f2bf(acc[i][2]); v.w = f2bf(acc[i][3]);
            *(ushort4*)(Ybf + (size_t)row * FOUT + cg * 4) = v;
        }
    }

    // fused att dots
    float4 asv = ((const float4*)attS)[cg];
    float4 adv = ((const float4*)attD)[cg];
    int head = (H == 2) ? (cg >> 4) : 0;
#pragma unroll
    for (int i = 0; i < 8; i++) {
        float ps = acc[i][0] * asv.x + acc[i][1] * asv.y + acc[i][2] * asv.z + acc[i][3] * asv.w;
        float pd = acc[i][0] * adv.x + acc[i][1] * adv.y + acc[i][2] * adv.z + acc[i][3] * adv.w;
#pragma unroll
        for (int o = 1; o <= 8; o <<= 1) { ps += __shfl_xor(ps, o); pd += __shfl_xor(pd, o); }
        int row = rowbase + r0 + i;
        if ((tid & 15) == 0 && row < N) {
            as_[(size_t)row * H + head] = ps;
            ad_[(size_t)row * H + head] = pd;
        }
    }
}

// ---------------- P3 fused with layer-1 GEMM: blocks [0,G) scatter, rest gemm ----------------
__global__ __launch_bounds__(256) void scatter_gemm1_kernel(const int* __restrict__ ei, int E,
                                                            int K, int CH, int* __restrict__ bcur,
                                                            unsigned int* __restrict__ bkt,
                                                            const float* __restrict__ X,
                                                            const float* __restrict__ W1,
                                                            const float* __restrict__ attS,
                                                            const float* __restrict__ attD,
                                                            unsigned short* __restrict__ Ybf,
                                                            float* __restrict__ as_,
                                                            float* __restrict__ ad_, int N, int G) {
    __shared__ float sX[64 * 68];       // 17.4 KB
    __shared__ float sW[64 * 128];      // 32 KB
    if (blockIdx.x < G) {
        int* hist = (int*)sW;           // carve scatter LDS out of gemm buffers
        int* base = hist + MAXK;
        int tid = threadIdx.x;
        for (int i = tid; i < K; i += 256) hist[i] = 0;
        __syncthreads();
        int lo = blockIdx.x * CH;
        int hi = lo + CH; if (hi > E) hi = E;
        for (int e = lo + tid; e < hi; e += 256)
            atomicAdd(&hist[ei[(size_t)E + e] >> LOG_NB], 1);
        __syncthreads();
        for (int i = tid; i < K; i += 256) {
            int c = hist[i];
            base[i] = c ? atomicAdd(&bcur[i], c) : 0;
        }
        __syncthreads();
        for (int i = tid; i < K; i += 256) hist[i] = 0;
        __syncthreads();
        for (int e = lo + tid; e < hi; e += 256) {
            int s = ei[e];
            int d = ei[(size_t)E + e];
            int k = d >> LOG_NB;
            int r = atomicAdd(&hist[k], 1);
            bkt[(size_t)base[k] + r] = (unsigned int)s | ((unsigned int)d << 16);
        }
    } else {
        gemm_att_body<128, 2>(X, W1, attS, attD, Ybf, as_, ad_, N, blockIdx.x - G, sX, sW);
    }
}

// ---------------- standalone GEMM (layer 2) ----------------
template <int FOUT, int H>
__global__ __launch_bounds__(256) void gemm_att_kernel(const float* __restrict__ X,
                                                       const float* __restrict__ W,
                                                       const float* __restrict__ attS,
                                                       const float* __restrict__ attD,
                                                       unsigned short* __restrict__ Ybf,
                                                       float* __restrict__ as_,
                                                       float* __restrict__ ad_, int N) {
    constexpr int ROWS = 8192 / FOUT;
    __shared__ float sX[ROWS * 68];
    __shared__ float sW[64 * FOUT];
    gemm_att_body<FOUT, H>(X, W, attS, attD, Ybf, as_, ad_, N, blockIdx.x, sX, sW);
}

// ---------------- P4: per-bucket CSR finalize (parallel prefix; +1 self slot per node) ----------------
__global__ __launch_bounds__(256) void sort_finalize_kernel(const unsigned int* __restrict__ bkt,
                                                            const int* __restrict__ boff,
                                                            int* __restrict__ off,
                                                            unsigned int* __restrict__ csrc, int N) {
    __shared__ int nhist[NB];
    __shared__ int part[256];
    __shared__ int loff[NB];
    int k = blockIdx.x;
    int tid = threadIdx.x;
    int node0 = k << LOG_NB;
    int nh = N - node0; if (nh > NB) nh = NB;
    int beg = boff[k], end = boff[k + 1];
    for (int i = tid; i < NB; i += 256) nhist[i] = 0;
    __syncthreads();
    for (int e = beg + tid; e < end; e += 256)
        atomicAdd(&nhist[(bkt[e] >> 16) - node0], 1);
    __syncthreads();
    int i0 = 2 * tid, i1 = 2 * tid + 1;
    int v0 = (i0 < nh) ? nhist[i0] + 1 : 0;
    int v1 = (i1 < nh) ? nhist[i1] + 1 : 0;
    part[tid] = v0 + v1;
    __syncthreads();
    for (int o = 1; o < 256; o <<= 1) {
        int t = (tid >= o) ? part[tid - o] : 0;
        __syncthreads();
        part[tid] += t;
        __syncthreads();
    }
    int gbase = beg + node0;   // node0 self slots precede this bucket
    int base = gbase + ((tid > 0) ? part[tid - 1] : 0);
    if (i0 < nh) loff[i0] = base;
    if (i1 < nh) loff[i1] = base + v0;
    __syncthreads();
    for (int i = tid; i < nh; i += 256) {
        int node = node0 + i;
        off[node] = loff[i];
        csrc[loff[i]] = (unsigned int)node | ((unsigned int)node << 16);  // self-loop first
        nhist[i] = loff[i] + 1;
    }
    if (node0 + nh == N && tid == 0) off[N] = gbase + part[255];
    __syncthreads();
    for (int e = beg + tid; e < end; e += 256) {
        unsigned int p = bkt[e];
        int pos = atomicAdd(&nhist[(p >> 16) - node0], 1);
        csrc[pos] = p;   // keep packed (src | dst<<16)
    }
}

// ---------------- layer-1 softmax+aggregate: one wave per NODE, both heads ----------------
// Inline logits (as_ is L2-resident); gather loop uses 32-bit byte offsets. fp32 out.

__global__ __launch_bounds__(256) void agg1_kernel(const unsigned short* __restrict__ xl,
                                                   const float* __restrict__ as_,
                                                   const float* __restrict__ ad_,
                                                   const float* __restrict__ bias,
                                                   const int* __restrict__ off,
                                                   const unsigned int* __restrict__ csrc,
                                                   float* __restrict__ out, int N) {
    __shared__ float4 sps[4][64];   // {p0, p1, as_int(byteoff), -}
    int wiw  = threadIdx.x >> 6;
    int lane = threadIdx.x & 63;
    int node = blockIdx.x * 4 + wiw;
    if (node >= N) return;
    int beg = off[node], end = off[node + 1];
    int deg = end - beg;
    float2 adn = ((const float2*)ad_)[node];

    int cl  = lane & 15;
    int sub = lane >> 4;
    int hd1 = (cl >> 3) & 1;
    float acc[8];
#pragma unroll
    for (int i = 0; i < 8; i++) acc[i] = 0.f;
    const char* xbase = (const char*)xl + cl * 16;   // + src*256

    if (deg <= 64) {
        int so = 0;
        float t0 = -1e30f, t1 = -1e30f;
        if (lane < deg) {
            int s = (int)(csrc[beg + lane] & 0xFFFFu);
            so = s << 8;                       // byte offset of row
            float2 asv = ((const float2*)as_)[s];
            t0 = asv.x + adn.x; t0 = t0 > 0.f ? t0 : NEG_SLOPE * t0;
            t1 = asv.y + adn.y; t1 = t1 > 0.f ? t1 : NEG_SLOPE * t1;
        }
        float m0 = t0, m1 = t1;
#pragma unroll
        for (int o = 32; o; o >>= 1) {
            m0 = fmaxf(m0, __shfl_xor(m0, o));
            m1 = fmaxf(m1, __shfl_xor(m1, o));
        }
        float e0 = (lane < deg) ? __expf(t0 - m0) : 0.f;
        float e1 = (lane < deg) ? __expf(t1 - m1) : 0.f;
        float s0 = e0, s1 = e1;
#pragma unroll
        for (int o = 32; o; o >>= 1) { s0 += __shfl_xor(s0, o); s1 += __shfl_xor(s1, o); }
        sps[wiw][lane] = make_float4(e0 / s0, e1 / s1, __int_as_float(so), 0.f);
        int iters = (deg + 3) >> 2;
#pragma unroll 8
        for (int j = 0; j < iters; j++) {
            float4 q = sps[wiw][j * 4 + sub];
            float a  = hd1 ? q.y : q.x;
            uint4 v  = *(const uint4*)(xbase + __float_as_int(q.z));
            acc[0] = fmaf(a, bf_lo(v.x), acc[0]); acc[1] = fmaf(a, bf_hi(v.x), acc[1]);
            acc[2] = fmaf(a, bf_lo(v.y), acc[2]); acc[3] = fmaf(a, bf_hi(v.y), acc[3]);
            acc[4] = fmaf(a, bf_lo(v.z), acc[4]); acc[5] = fmaf(a, bf_hi(v.z), acc[5]);
            acc[6] = fmaf(a, bf_lo(v.w), acc[6]); acc[7] = fmaf(a, bf_hi(v.w), acc[7]);
        }
    } else {
        // 3-pass fallback (deg > 64)
        float m0 = -1e30f, m1 = -1e30f;
        for (int b = beg; b < end; b += 64) {
            int e = b + lane;
            if (e < end) {
                int s = (int)(csrc[e] & 0xFFFFu);
                float2 asv = ((const float2*)as_)[s];
                float t0 = asv.x + adn.x; t0 = t0 > 0.f ? t0 : NEG_SLOPE * t0;
                float t1 = asv.y + adn.y; t1 = t1 > 0.f ? t1 : NEG_SLOPE * t1;
                m0 = fmaxf(m0, t0); m1 = fmaxf(m1, t1);
            }
        }
#pragma unroll
        for (int o = 32; o; o >>= 1) {
            m0 = fmaxf(m0, __shfl_xor(m0, o));
            m1 = fmaxf(m1, __shfl_xor(m1, o));
        }
        float s0 = 0.f, s1 = 0.f;
        for (int b = beg; b < end; b += 64) {
            int e = b + lane;
            if (e < end) {
                int s = (int)(csrc[e] & 0xFFFFu);
                float2 asv = ((const float2*)as_)[s];
                float t0 = asv.x + adn.x; t0 = t0 > 0.f ? t0 : NEG_SLOPE * t0;
                float t1 = asv.y + adn.y; t1 = t1 > 0.f ? t1 : NEG_SLOPE * t1;
                s0 += __expf(t0 - m0); s1 += __expf(t1 - m1);
            }
        }
#pragma unroll
        for (int o = 32; o; o >>= 1) { s0 += __shfl_xor(s0, o); s1 += __shfl_xor(s1, o); }
        float i0 = 1.f / s0, i1 = 1.f / s1;
        for (int b = beg; b < end; b += 64) {
            int cnt = end - b; if (cnt > 64) cnt = 64;
            float p0 = 0.f, p1 = 0.f; int so = 0;
            if (lane < cnt) {
                int s = (int)(csrc[b + lane] & 0xFFFFu);
                so = s << 8;
                float2 asv = ((const float2*)as_)[s];
                float t0 = asv.x + adn.x; t0 = t0 > 0.f ? t0 : NEG_SLOPE * t0;
                float t1 = asv.y + adn.y; t1 = t1 > 0.f ? t1 : NEG_SLOPE * t1;
                p0 = __expf(t0 - m0) * i0; p1 = __expf(t1 - m1) * i1;
            }
            sps[wiw][lane] = make_float4(p0, p1, __int_as_float(so), 0.f);
            int iters = (cnt + 3) >> 2;
#pragma unroll 8
            for (int j = 0; j < iters; j++) {
                float4 q = sps[wiw][j * 4 + sub];
                float a  = hd1 ? q.y : q.x;
                uint4 v  = *(const uint4*)(xbase + __float_as_int(q.z));
                acc[0] = fmaf(a, bf_lo(v.x), acc[0]); acc[1] = fmaf(a, bf_hi(v.x), acc[1]);
                acc[2] = fmaf(a, bf_lo(v.y), acc[2]); acc[3] = fmaf(a, bf_hi(v.y), acc[3]);
                acc[4] = fmaf(a, bf_lo(v.z), acc[4]); acc[5] = fmaf(a, bf_hi(v.z), acc[5]);
                acc[6] = fmaf(a, bf_lo(v.w), acc[6]); acc[7] = fmaf(a, bf_hi(v.w), acc[7]);
            }
        }
    }
#pragma unroll
    for (int o = 16; o <= 32; o <<= 1)
#pragma unroll
        for (int i = 0; i < 8; i++) acc[i] += __shfl_xor(acc[i], o);
    if (sub == 0) {
        float* op = out + (size_t)node * 128 + cl * 8;
        const float* bp = bias + cl * 8;
#pragma unroll
        for (int i = 0; i < 8; i++) op[i] = fmaxf(acc[i] + bp[i], 0.f);
    }
}

// ---------------- layer-2 softmax+aggregate: one wave per node, H=1, fp32 out ----------------

__global__ __launch_bounds__(256) void agg2_kernel(const unsigned short* __restrict__ xl,
                                                   const float* __restrict__ as_,
                                                   const float* __restrict__ ad_,
                                                   const float* __restrict__ bias,
                                                   const int* __restrict__ off,
                                                   const unsigned int* __restrict__ csrc,
                                                   float* __restrict__ out, int N) {
    __shared__ float2 sps[4][64];   // {p, as_int(byteoff)}
    int wiw  = threadIdx.x >> 6;
    int lane = threadIdx.x & 63;
    int node = blockIdx.x * 4 + wiw;
    if (node >= N) return;
    int beg = off[node], end = off[node + 1];
    int deg = end - beg;
    float adn = ad_[node];

    int cl  = lane & 7;
    int sub = lane >> 3;
    float acc[8];
#pragma unroll
    for (int i = 0; i < 8; i++) acc[i] = 0.f;
    const char* xbase = (const char*)xl + cl * 16;   // + src*128

    if (deg <= 64) {
        int so = 0;
        float t = -1e30f;
        if (lane < deg) {
            int s = (int)(csrc[beg + lane] & 0xFFFFu);
            so = s << 7;
            t = as_[s] + adn;
            t = t > 0.f ? t : NEG_SLOPE * t;
        }
        float m = t;
#pragma unroll
        for (int o = 32; o; o >>= 1) m = fmaxf(m, __shfl_xor(m, o));
        float evv = (lane < deg) ? __expf(t - m) : 0.f;
        float sum = evv;
#pragma unroll
        for (int o = 32; o; o >>= 1) sum += __shfl_xor(sum, o);
        sps[wiw][lane] = make_float2(evv / sum, __int_as_float(so));
        int iters = (deg + 7) >> 3;
#pragma unroll 8
        for (int j = 0; j < iters; j++) {
            float2 q = sps[wiw][j * 8 + sub];
            float a  = q.x;
            uint4 v  = *(const uint4*)(xbase + __float_as_int(q.y));
            acc[0] = fmaf(a, bf_lo(v.x), acc[0]); acc[1] = fmaf(a, bf_hi(v.x), acc[1]);
            acc[2] = fmaf(a, bf_lo(v.y), acc[2]); acc[3] = fmaf(a, bf_hi(v.y), acc[3]);
            acc[4] = fmaf(a, bf_lo(v.z), acc[4]); acc[5] = fmaf(a, bf_hi(v.z), acc[5]);
            acc[6] = fmaf(a, bf_lo(v.w), acc[6]); acc[7] = fmaf(a, bf_hi(v.w), acc[7]);
        }
    } else {
        float m = -1e30f;
        for (int b = beg; b < end; b += 64) {
            int e = b + lane;
            if (e < end) {
                float t = as_[csrc[e] & 0xFFFFu] + adn;
                t = t > 0.f ? t : NEG_SLOPE * t;
                m = fmaxf(m, t);
            }
        }
#pragma unroll
        for (int o = 32; o; o >>= 1) m = fmaxf(m, __shfl_xor(m, o));
        float sum = 0.f;
        for (int b = beg; b < end; b += 64) {
            int e = b + lane;
            if (e < end) {
                float t = as_[csrc[e] & 0xFFFFu] + adn;
                t = t > 0.f ? t : NEG_SLOPE * t;
                sum += __expf(t - m);
            }
        }
#pragma unroll
        for (int o = 32; o; o >>= 1) sum += __shfl_xor(sum, o);
        float inv = 1.f / sum;
        for (int b = beg; b < end; b += 64) {
            int cnt = end - b; if (cnt > 64) cnt = 64;
            float p = 0.f; int so = 0;
            if (lane < cnt) {
                int s = (int)(csrc[b + lane] & 0xFFFFu);
                so = s << 7;
                float t = as_[s] + adn;
                t = t > 0.f ? t : NEG_SLOPE * t;
                p = __expf(t - m) * inv;
            }
            sps[wiw][lane] = make_float2(p, __int_as_float(so));
            int iters = (cnt + 7) >> 3;
#pragma unroll 8
            for (int j = 0; j < iters; j++) {
                float2 q = sps[wiw][j * 8 + sub];
                float a  = q.x;
                uint4 v  = *(const uint4*)(xbase + __float_as_int(q.y));
                acc[0] = fmaf(a, bf_lo(v.x), acc[0]); acc[1] = fmaf(a, bf_hi(v.x), acc[1]);
                acc[2] = fmaf(a, bf_lo(v.y), acc[2]); acc[3] = fmaf(a, bf_hi(v.y), acc[3]);
                acc[4] = fmaf(a, bf_lo(v.z), acc[4]); acc[5] = fmaf(a, bf_hi(v.z), acc[5]);
                acc[6] = fmaf(a, bf_lo(v.w), acc[6]); acc[7] = fmaf(a, bf_hi(v.w), acc[7]);
            }
        }
    }
#pragma unroll
    for (int o = 8; o <= 32; o <<= 1)
#pragma unroll
        for (int i = 0; i < 8; i++) acc[i] += __shfl_xor(acc[i], o);
    if (sub == 0) {
        float* op = out + (size_t)node * 64 + cl * 8;
        const float* bp = bias + cl * 8;
#pragma unroll
        for (int i = 0; i < 8; i++) op[i] = fmaxf(acc[i] + bp[i], 0.f);
    }
}

// ---------------- launcher ----------------

extern "C" void kernel_launch(void* const* d_in, const int* in_sizes, int n_in,
                              void* d_out, int out_size, void* d_ws, size_t ws_size,
                              hipStream_t stream) {
    const float* x        = (const float*)d_in[0];
    const int*   ei       = (const int*)d_in[1];   // int32 per harness convention
    const float* W1       = (const float*)d_in[2];
    const float* attS1    = (const float*)d_in[3];
    const float* attD1    = (const float*)d_in[4];
    const float* b1       = (const float*)d_in[5];
    const float* W2       = (const float*)d_in[6];
    const float* attS2    = (const float*)d_in[7];
    const float* attD2    = (const float*)d_in[8];
    const float* b2       = (const float*)d_in[9];
    float* out            = (float*)d_out;

    int N  = in_sizes[0] / 128;
    int E  = in_sizes[1] / 2;
    int EE = E + N;                    // with self-loops
    int K  = (N + NB - 1) >> LOG_NB;   // buckets (98 for N=50000)

    char* w = (char*)d_ws;
    auto alloc = [&](size_t bytes) -> void* {
        void* p = (void*)w;
        w += (bytes + 255) & ~(size_t)255;
        return p;
    };
    int*   bcnt = (int*)alloc((size_t)(K + 1) * 4);
    int*   boff = (int*)alloc((size_t)(K + 1) * 4);
    int*   bcur = (int*)alloc((size_t)(K + 1) * 4);
    int*   off  = (int*)alloc((size_t)(N + 1) * 4);
    unsigned int* csrc = (unsigned int*)alloc((size_t)EE * 4);
    unsigned int* bkt  = (unsigned int*)alloc((size_t)E * 4);           // OWN buffer (no alias!)
    unsigned short* xl1 = (unsigned short*)alloc((size_t)N * 128 * 2);  // bf16; reused as xl2
    float* sd1  = (float*)alloc((size_t)N * 2 * 4);
    float* dd1  = (float*)alloc((size_t)N * 2 * 4);
    float* h1   = (float*)alloc((size_t)N * 128 * 4);                   // fp32

    unsigned short* xl2 = xl1;               // layer-2 xl (bf16), xl1 dead by then
    float* sd2 = sd1;
    float* dd2 = dd1;

    hipMemsetAsync(bcnt, 0, (size_t)(K + 1) * 4, stream);

    int G   = 256;
    int CH  = (E + G - 1) / G;
    int GB1 = (N + 63) / 64;    // gemm1 blocks
    sort_count_kernel<<<G, 256, 0, stream>>>(ei, E, K, CH, bcnt);
    sort_scan_kernel<<<1, MAXK, 0, stream>>>(bcnt, boff, bcur, K, E);
    // fused: scatter (blocks [0,G)) + layer-1 GEMM (blocks [G, G+GB1)) — independent work,
    // bkt and xl1 are now distinct buffers so concurrent writes are safe.
    scatter_gemm1_kernel<<<G + GB1, 256, 0, stream>>>(ei, E, K, CH, bcur, bkt,
                                                      x, W1, attS1, attD1, xl1, sd1, dd1, N, G);
    sort_finalize_kernel<<<K, 256, 0, stream>>>(bkt, boff, off, csrc, N);

    // ---- layer 1 aggregate ----
    agg1_kernel<<<(N + 3) / 4, 256, 0, stream>>>(xl1, sd1, dd1, b1, off, csrc, h1, N);

    // ---- layer 2 ----
    gemm_att_kernel<64, 1><<<(N + 127) / 128, 256, 0, stream>>>(h1, W2, attS2, attD2, xl2, sd2, dd2, N);
    agg2_kernel<<<(N + 3) / 4, 256, 0, stream>>>(xl2, sd2, dd2, b2, off, csrc, out, N);
}

// Round 14
// 319.082 us; speedup vs baseline: 1.1181x; 1.0246x over previous
//
#include <hip/hip_runtime.h>
#include <cstdint>
#include <cstddef>

#define NEG_SLOPE 0.2f

// Edge packing relies on N <= 65536 (here N = 50000): edge = src | (dst<<16).
// Self-loops are NOT sorted: placed analytically (one per node, first slot).
// csrc[] stores the PACKED edge (src in low 16, dst in high 16).
// NOTE: bkt MUST NOT alias xl1 — scatter and gemm1 run concurrently (fused kernel).
#define NB 512        // nodes per bucket
#define LOG_NB 9
#define MAXK 512

__device__ inline unsigned short f2bf(float f) {          // RNE fp32->bf16
    unsigned int u = __float_as_uint(f);
    u += 0x7FFFu + ((u >> 16) & 1u);
    return (unsigned short)(u >> 16);
}
__device__ inline float bf_lo(unsigned int u) { return __uint_as_float(u << 16); }
__device__ inline float bf_hi(unsigned int u) { return __uint_as_float(u & 0xFFFF0000u); }

// ---------------- P1: bucket histogram, 4-way wave-replicated (real edges only) ----------------
__global__ __launch_bounds__(256) void sort_count_kernel(const int* __restrict__ ei, int E,
                                                         int K, int CH, int* __restrict__ bcnt) {
    __shared__ int hist[4 * MAXK];
    int tid = threadIdx.x;
    int wiw = tid >> 6;
    for (int i = tid; i < K; i += 256) {
        hist[i] = 0; hist[MAXK + i] = 0; hist[2 * MAXK + i] = 0; hist[3 * MAXK + i] = 0;
    }
    __syncthreads();
    int lo = blockIdx.x * CH;
    int hi = lo + CH; if (hi > E) hi = E;
    for (int e = lo + tid; e < hi; e += 256)
        atomicAdd(&hist[wiw * MAXK + (ei[(size_t)E + e] >> LOG_NB)], 1);
    __syncthreads();
    for (int i = tid; i < K; i += 256) {
        int c = hist[i] + hist[MAXK + i] + hist[2 * MAXK + i] + hist[3 * MAXK + i];
        if (c) atomicAdd(&bcnt[i], c);
    }
}

// ---------------- P2: scan bucket counts ----------------
__global__ void sort_scan_kernel(const int* __restrict__ bcnt, int* __restrict__ boff,
                                 int* __restrict__ bcur, int K, int E) {
    __shared__ int buf[MAXK];
    int tid = threadIdx.x;   // 512 threads
    int v = (tid < K) ? bcnt[tid] : 0;
    buf[tid] = v;
    __syncthreads();
    for (int o = 1; o < MAXK; o <<= 1) {
        int t = (tid >= o) ? buf[tid - o] : 0;
        __syncthreads();
        buf[tid] += t;
        __syncthreads();
    }
    if (tid < K) {
        int ex = buf[tid] - v;
        boff[tid] = ex;
        bcur[tid] = ex;
    }
    if (tid == K) boff[K] = E;
}

// ---- GEMM + fused att dots body: K-tiles of 32 (low LDS, high occupancy) ----
// ROWS=64 both layers; RR = rows/thread (8 for FOUT=128, 4 for FOUT=64).

template <int FOUT, int H, int ROWS>
__device__ __forceinline__ void gemm_att_body(const float* __restrict__ X,
                                              const float* __restrict__ W,
                                              const float* __restrict__ attS,
                                              const float* __restrict__ attD,
                                              unsigned short* __restrict__ Ybf,
                                              float* __restrict__ as_,
                                              float* __restrict__ ad_, int N, int bid,
                                              float* sX, float* sW) {
    constexpr int CG  = FOUT / 4;
    constexpr int RR  = (ROWS * FOUT) / 1024;   // rows per thread
    constexpr int LDX = 36;                     // 32 + 4 pad
    int tid = threadIdx.x;
    int rowbase = bid * ROWS;
    int cg = tid % CG;
    int rg = tid / CG;
    int r0 = rg * RR;

    float acc[RR][4];
#pragma unroll
    for (int i = 0; i < RR; i++)
#pragma unroll
        for (int c = 0; c < 4; c++) acc[i][c] = 0.f;

    for (int k0 = 0; k0 < 128; k0 += 32) {
        __syncthreads();
        for (int idx = tid; idx < ROWS * 8; idx += 256) {
            int r = idx >> 3, q = idx & 7;
            int row = rowbase + r;
            float4 val = (row < N) ? *(const float4*)&X[(size_t)row * 128 + k0 + q * 4]
                                   : make_float4(0.f, 0.f, 0.f, 0.f);
            *(float4*)&sX[r * LDX + q * 4] = val;
        }
        for (int idx = tid; idx < 8 * FOUT; idx += 256)
            *(float4*)&sW[idx * 4] = *(const float4*)&W[(size_t)k0 * FOUT + idx * 4];
        __syncthreads();
        for (int k = 0; k < 32; k += 4) {
            float4 xr[RR];
#pragma unroll
            for (int i = 0; i < RR; i++)
                xr[i] = *(const float4*)&sX[(r0 + i) * LDX + k];
#pragma unroll
            for (int kk = 0; kk < 4; kk++) {
                float4 wv = ((const float4*)(sW + (size_t)(k + kk) * FOUT))[cg];
#pragma unroll
                for (int i = 0; i < RR; i++) {
                    float xv = (&xr[i].x)[kk];
                    acc[i][0] = fmaf(xv, wv.x, acc[i][0]);
                    acc[i][1] = fmaf(xv, wv.y, acc[i][1]);
                    acc[i][2] = fmaf(xv, wv.z, acc[i][2]);
                    acc[i][3] = fmaf(xv, wv.w, acc[i][3]);
                }
            }
        }
    }

    // store bf16 Y
#pragma unroll
    for (int i = 0; i < RR; i++) {
        int row = rowbase + r0 + i;
        if (row < N) {
            ushort4 v;
            v.x = f2bf(acc[i][0]); v.y = f2bf(acc[i][1]);
            v.z = f2bf(acc[i][2]); v.w = f2bf(acc[i][3]);
            *(ushort4*)(Ybf + (size_t)row * FOUT + cg * 4) = v;
        }
    }

    // fused att dots: each row's head-dot reduces over its 16 cg-threads (16-aligned lane group)
    float4 asv = ((const float4*)attS)[cg];
    float4 adv = ((const float4*)attD)[cg];
    int head = (H == 2) ? (cg >> 4) : 0;
#pragma unroll
    for (int i = 0; i < RR; i++) {
        float ps = acc[i][0] * asv.x + acc[i][1] * asv.y + acc[i][2] * asv.z + acc[i][3] * asv.w;
        float pd = acc[i][0] * adv.x + acc[i][1] * adv.y + acc[i][2] * adv.z + acc[i][3] * adv.w;
#pragma unroll
        for (int o = 1; o <= 8; o <<= 1) { ps += __shfl_xor(ps, o); pd += __shfl_xor(pd, o); }
        int row = rowbase + r0 + i;
        if ((tid & 15) == 0 && row < N) {
            as_[(size_t)row * H + head] = ps;
            ad_[(size_t)row * H + head] = pd;
        }
    }
}

// ---------------- P3 fused with layer-1 GEMM: blocks [0,G) scatter, rest gemm ----------------
__global__ __launch_bounds__(256) void scatter_gemm1_kernel(const int* __restrict__ ei, int E,
                                                            int K, int CH, int* __restrict__ bcur,
                                                            unsigned int* __restrict__ bkt,
                                                            const float* __restrict__ X,
                                                            const float* __restrict__ W1,
                                                            const float* __restrict__ attS,
                                                            const float* __restrict__ attD,
                                                            unsigned short* __restrict__ Ybf,
                                                            float* __restrict__ as_,
                                                            float* __restrict__ ad_, int N, int G) {
    __shared__ float sX[64 * 36];       // 9.2 KB
    __shared__ float sW[32 * 128];      // 16.4 KB
    if (blockIdx.x < G) {
        int* hist = (int*)sX;           // [4][MAXK] = 8 KB <= 9.2 KB
        int* base = (int*)sW;           // MAXK
        int* cur2 = (int*)sW + MAXK;    // MAXK
        int tid = threadIdx.x;
        int wiw = tid >> 6;
        for (int i = tid; i < K; i += 256) {
            hist[i] = 0; hist[MAXK + i] = 0; hist[2 * MAXK + i] = 0; hist[3 * MAXK + i] = 0;
        }
        __syncthreads();
        int lo = blockIdx.x * CH;
        int hi = lo + CH; if (hi > E) hi = E;
        for (int e = lo + tid; e < hi; e += 256)
            atomicAdd(&hist[wiw * MAXK + (ei[(size_t)E + e] >> LOG_NB)], 1);
        __syncthreads();
        for (int i = tid; i < K; i += 256) {
            int c = hist[i] + hist[MAXK + i] + hist[2 * MAXK + i] + hist[3 * MAXK + i];
            base[i] = c ? atomicAdd(&bcur[i], c) : 0;
            cur2[i] = 0;
        }
        __syncthreads();
        for (int e = lo + tid; e < hi; e += 256) {
            int s = ei[e];
            int d = ei[(size_t)E + e];
            int k = d >> LOG_NB;
            int r = atomicAdd(&cur2[k], 1);
            bkt[(size_t)base[k] + r] = (unsigned int)s | ((unsigned int)d << 16);
        }
    } else {
        gemm_att_body<128, 2, 64>(X, W1, attS, attD, Ybf, as_, ad_, N, blockIdx.x - G, sX, sW);
    }
}

// ---------------- standalone GEMM (layer 2): FOUT=64, ROWS=64, RR=4 ----------------
__global__ __launch_bounds__(256) void gemm2_kernel(const float* __restrict__ X,
                                                    const float* __restrict__ W,
                                                    const float* __restrict__ attS,
                                                    const float* __restrict__ attD,
                                                    unsigned short* __restrict__ Ybf,
                                                    float* __restrict__ as_,
                                                    float* __restrict__ ad_, int N) {
    __shared__ float sX[64 * 36];   // 9.2 KB
    __shared__ float sW[32 * 64];   // 8 KB
    gemm_att_body<64, 1, 64>(X, W, attS, attD, Ybf, as_, ad_, N, blockIdx.x, sX, sW);
}

// ---------------- P4: per-bucket CSR finalize (replicated hist; +1 self slot per node) ----------------
__global__ __launch_bounds__(256) void sort_finalize_kernel(const unsigned int* __restrict__ bkt,
                                                            const int* __restrict__ boff,
                                                            int* __restrict__ off,
                                                            unsigned int* __restrict__ csrc, int N) {
    __shared__ int nhist[4 * NB];   // 8 KB
    __shared__ int part[256];
    __shared__ int loff[NB];
    int k = blockIdx.x;
    int tid = threadIdx.x;
    int wiw = tid >> 6;
    int node0 = k << LOG_NB;
    int nh = N - node0; if (nh > NB) nh = NB;
    int beg = boff[k], end = boff[k + 1];
    for (int i = tid; i < NB; i += 256) {
        nhist[i] = 0; nhist[NB + i] = 0; nhist[2 * NB + i] = 0; nhist[3 * NB + i] = 0;
    }
    __syncthreads();
    for (int e = beg + tid; e < end; e += 256)
        atomicAdd(&nhist[wiw * NB + ((bkt[e] >> 16) - node0)], 1);
    __syncthreads();
    int i0 = 2 * tid, i1 = 2 * tid + 1;
    int v0 = (i0 < nh) ? nhist[i0] + nhist[NB + i0] + nhist[2 * NB + i0] + nhist[3 * NB + i0] + 1 : 0;
    int v1 = (i1 < nh) ? nhist[i1] + nhist[NB + i1] + nhist[2 * NB + i1] + nhist[3 * NB + i1] + 1 : 0;
    part[tid] = v0 + v1;
    __syncthreads();
    for (int o = 1; o < 256; o <<= 1) {
        int t = (tid >= o) ? part[tid - o] : 0;
        __syncthreads();
        part[tid] += t;
        __syncthreads();
    }
    int gbase = beg + node0;   // node0 self slots precede this bucket
    int base = gbase + ((tid > 0) ? part[tid - 1] : 0);
    if (i0 < nh) loff[i0] = base;
    if (i1 < nh) loff[i1] = base + v0;
    __syncthreads();
    for (int i = tid; i < nh; i += 256) {
        int node = node0 + i;
        off[node] = loff[i];
        csrc[loff[i]] = (unsigned int)node | ((unsigned int)node << 16);  // self-loop first
        nhist[i] = loff[i] + 1;    // single-copy cursor
    }
    if (node0 + nh == N && tid == 0) off[N] = gbase + part[255];
    __syncthreads();
    for (int e = beg + tid; e < end; e += 256) {
        unsigned int p = bkt[e];
        int pos = atomicAdd(&nhist[(p >> 16) - node0], 1);
        csrc[pos] = p;   // keep packed (src | dst<<16)
    }
}

// ---------------- layer-1 softmax+aggregate: one wave per NODE, both heads ----------------
// Inline logits (as_ is L2-resident); gather loop uses 32-bit byte offsets. fp32 out.

__global__ __launch_bounds__(256) void agg1_kernel(const unsigned short* __restrict__ xl,
                                                   const float* __restrict__ as_,
                                                   const float* __restrict__ ad_,
                                                   const float* __restrict__ bias,
                                                   const int* __restrict__ off,
                                                   const unsigned int* __restrict__ csrc,
                                                   float* __restrict__ out, int N) {
    __shared__ float4 sps[4][64];   // {p0, p1, as_int(byteoff), -}
    int wiw  = threadIdx.x >> 6;
    int lane = threadIdx.x & 63;
    int node = blockIdx.x * 4 + wiw;
    if (node >= N) return;
    int beg = off[node], end = off[node + 1];
    int deg = end - beg;
    float2 adn = ((const float2*)ad_)[node];

    int cl  = lane & 15;
    int sub = lane >> 4;
    int hd1 = (cl >> 3) & 1;
    float acc[8];
#pragma unroll
    for (int i = 0; i < 8; i++) acc[i] = 0.f;
    const char* xbase = (const char*)xl + cl * 16;   // + src*256

    if (deg <= 64) {
        int so = 0;
        float t0 = -1e30f, t1 = -1e30f;
        if (lane < deg) {
            int s = (int)(csrc[beg + lane] & 0xFFFFu);
            so = s << 8;                       // byte offset of row
            float2 asv = ((const float2*)as_)[s];
            t0 = asv.x + adn.x; t0 = t0 > 0.f ? t0 : NEG_SLOPE * t0;
            t1 = asv.y + adn.y; t1 = t1 > 0.f ? t1 : NEG_SLOPE * t1;
        }
        float m0 = t0, m1 = t1;
#pragma unroll
        for (int o = 32; o; o >>= 1) {
            m0 = fmaxf(m0, __shfl_xor(m0, o));
            m1 = fmaxf(m1, __shfl_xor(m1, o));
        }
        float e0 = (lane < deg) ? __expf(t0 - m0) : 0.f;
        float e1 = (lane < deg) ? __expf(t1 - m1) : 0.f;
        float s0 = e0, s1 = e1;
#pragma unroll
        for (int o = 32; o; o >>= 1) { s0 += __shfl_xor(s0, o); s1 += __shfl_xor(s1, o); }
        sps[wiw][lane] = make_float4(e0 / s0, e1 / s1, __int_as_float(so), 0.f);
        int iters = (deg + 3) >> 2;
#pragma unroll 8
        for (int j = 0; j < iters; j++) {
            float4 q = sps[wiw][j * 4 + sub];
            float a  = hd1 ? q.y : q.x;
            uint4 v  = *(const uint4*)(xbase + __float_as_int(q.z));
            acc[0] = fmaf(a, bf_lo(v.x), acc[0]); acc[1] = fmaf(a, bf_hi(v.x), acc[1]);
            acc[2] = fmaf(a, bf_lo(v.y), acc[2]); acc[3] = fmaf(a, bf_hi(v.y), acc[3]);
            acc[4] = fmaf(a, bf_lo(v.z), acc[4]); acc[5] = fmaf(a, bf_hi(v.z), acc[5]);
            acc[6] = fmaf(a, bf_lo(v.w), acc[6]); acc[7] = fmaf(a, bf_hi(v.w), acc[7]);
        }
    } else {
        // 3-pass fallback (deg > 64)
        float m0 = -1e30f, m1 = -1e30f;
        for (int b = beg; b < end; b += 64) {
            int e = b + lane;
            if (e < end) {
                int s = (int)(csrc[e] & 0xFFFFu);
                float2 asv = ((const float2*)as_)[s];
                float t0 = asv.x + adn.x; t0 = t0 > 0.f ? t0 : NEG_SLOPE * t0;
                float t1 = asv.y + adn.y; t1 = t1 > 0.f ? t1 : NEG_SLOPE * t1;
                m0 = fmaxf(m0, t0); m1 = fmaxf(m1, t1);
            }
        }
#pragma unroll
        for (int o = 32; o; o >>= 1) {
            m0 = fmaxf(m0, __shfl_xor(m0, o));
            m1 = fmaxf(m1, __shfl_xor(m1, o));
        }
        float s0 = 0.f, s1 = 0.f;
        for (int b = beg; b < end; b += 64) {
            int e = b + lane;
            if (e < end) {
                int s = (int)(csrc[e] & 0xFFFFu);
                float2 asv = ((const float2*)as_)[s];
                float t0 = asv.x + adn.x; t0 = t0 > 0.f ? t0 : NEG_SLOPE * t0;
                float t1 = asv.y + adn.y; t1 = t1 > 0.f ? t1 : NEG_SLOPE * t1;
                s0 += __expf(t0 - m0); s1 += __expf(t1 - m1);
            }
        }
#pragma unroll
        for (int o = 32; o; o >>= 1) { s0 += __shfl_xor(s0, o); s1 += __shfl_xor(s1, o); }
        float i0 = 1.f / s0, i1 = 1.f / s1;
        for (int b = beg; b < end; b += 64) {
            int cnt = end - b; if (cnt > 64) cnt = 64;
            float p0 = 0.f, p1 = 0.f; int so = 0;
            if (lane < cnt) {
                int s = (int)(csrc[b + lane] & 0xFFFFu);
                so = s << 8;
                float2 asv = ((const float2*)as_)[s];
                float t0 = asv.x + adn.x; t0 = t0 > 0.f ? t0 : NEG_SLOPE * t0;
                float t1 = asv.y + adn.y; t1 = t1 > 0.f ? t1 : NEG_SLOPE * t1;
                p0 = __expf(t0 - m0) * i0; p1 = __expf(t1 - m1) * i1;
            }
            sps[wiw][lane] = make_float4(p0, p1, __int_as_float(so), 0.f);
            int iters = (cnt + 3) >> 2;
#pragma unroll 8
            for (int j = 0; j < iters; j++) {
                float4 q = sps[wiw][j * 4 + sub];
                float a  = hd1 ? q.y : q.x;
                uint4 v  = *(const uint4*)(xbase + __float_as_int(q.z));
                acc[0] = fmaf(a, bf_lo(v.x), acc[0]); acc[1] = fmaf(a, bf_hi(v.x), acc[1]);
                acc[2] = fmaf(a, bf_lo(v.y), acc[2]); acc[3] = fmaf(a, bf_hi(v.y), acc[3]);
                acc[4] = fmaf(a, bf_lo(v.z), acc[4]); acc[5] = fmaf(a, bf_hi(v.z), acc[5]);
                acc[6] = fmaf(a, bf_lo(v.w), acc[6]); acc[7] = fmaf(a, bf_hi(v.w), acc[7]);
            }
        }
    }
#pragma unroll
    for (int o = 16; o <= 32; o <<= 1)
#pragma unroll
        for (int i = 0; i < 8; i++) acc[i] += __shfl_xor(acc[i], o);
    if (sub == 0) {
        float* op = out + (size_t)node * 128 + cl * 8;
        const float* bp = bias + cl * 8;
#pragma unroll
        for (int i = 0; i < 8; i++) op[i] = fmaxf(acc[i] + bp[i], 0.f);
    }
}

// ---------------- layer-2 softmax+aggregate: one wave per node, H=1, fp32 out ----------------

__global__ __launch_bounds__(256) void agg2_kernel(const unsigned short* __restrict__ xl,
                                                   const float* __restrict__ as_,
                                                   const float* __restrict__ ad_,
                                                   const float* __restrict__ bias,
                                                   const int* __restrict__ off,
                                                   const unsigned int* __restrict__ csrc,
                                                   float* __restrict__ out, int N) {
    __shared__ float2 sps[4][64];   // {p, as_int(byteoff)}
    int wiw  = threadIdx.x >> 6;
    int lane = threadIdx.x & 63;
    int node = blockIdx.x * 4 + wiw;
    if (node >= N) return;
    int beg = off[node], end = off[node + 1];
    int deg = end - beg;
    float adn = ad_[node];

    int cl  = lane & 7;
    int sub = lane >> 3;
    float acc[8];
#pragma unroll
    for (int i = 0; i < 8; i++) acc[i] = 0.f;
    const char* xbase = (const char*)xl + cl * 16;   // + src*128

    if (deg <= 64) {
        int so = 0;
        float t = -1e30f;
        if (lane < deg) {
            int s = (int)(csrc[beg + lane] & 0xFFFFu);
            so = s << 7;
            t = as_[s] + adn;
            t = t > 0.f ? t : NEG_SLOPE * t;
        }
        float m = t;
#pragma unroll
        for (int o = 32; o; o >>= 1) m = fmaxf(m, __shfl_xor(m, o));
        float evv = (lane < deg) ? __expf(t - m) : 0.f;
        float sum = evv;
#pragma unroll
        for (int o = 32; o; o >>= 1) sum += __shfl_xor(sum, o);
        sps[wiw][lane] = make_float2(evv / sum, __int_as_float(so));
        int iters = (deg + 7) >> 3;
#pragma unroll 8
        for (int j = 0; j < iters; j++) {
            float2 q = sps[wiw][j * 8 + sub];
            float a  = q.x;
            uint4 v  = *(const uint4*)(xbase + __float_as_int(q.y));
            acc[0] = fmaf(a, bf_lo(v.x), acc[0]); acc[1] = fmaf(a, bf_hi(v.x), acc[1]);
            acc[2] = fmaf(a, bf_lo(v.y), acc[2]); acc[3] = fmaf(a, bf_hi(v.y), acc[3]);
            acc[4] = fmaf(a, bf_lo(v.z), acc[4]); acc[5] = fmaf(a, bf_hi(v.z), acc[5]);
            acc[6] = fmaf(a, bf_lo(v.w), acc[6]); acc[7] = fmaf(a, bf_hi(v.w), acc[7]);
        }
    } else {
        float m = -1e30f;
        for (int b = beg; b < end; b += 64) {
            int e = b + lane;
            if (e < end) {
                float t = as_[csrc[e] & 0xFFFFu] + adn;
                t = t > 0.f ? t : NEG_SLOPE * t;
                m = fmaxf(m, t);
            }
        }
#pragma unroll
        for (int o = 32; o; o >>= 1) m = fmaxf(m, __shfl_xor(m, o));
        float sum = 0.f;
        for (int b = beg; b < end; b += 64) {
            int e = b + lane;
            if (e < end) {
                float t = as_[csrc[e] & 0xFFFFu] + adn;
                t = t > 0.f ? t : NEG_SLOPE * t;
                sum += __expf(t - m);
            }
        }
#pragma unroll
        for (int o = 32; o; o >>= 1) sum += __shfl_xor(sum, o);
        float inv = 1.f / sum;
        for (int b = beg; b < end; b += 64) {
            int cnt = end - b; if (cnt > 64) cnt = 64;
            float p = 0.f; int so = 0;
            if (lane < cnt) {
                int s = (int)(csrc[b + lane] & 0xFFFFu);
                so = s << 7;
                float t = as_[s] + adn;
                t = t > 0.f ? t : NEG_SLOPE * t;
                p = __expf(t - m) * inv;
            }
            sps[wiw][lane] = make_float2(p, __int_as_float(so));
            int iters = (cnt + 7) >> 3;
#pragma unroll 8
            for (int j = 0; j < iters; j++) {
                float2 q = sps[wiw][j * 8 + sub];
                float a  = q.x;
                uint4 v  = *(const uint4*)(xbase + __float_as_int(q.y));
                acc[0] = fmaf(a, bf_lo(v.x), acc[0]); acc[1] = fmaf(a, bf_hi(v.x), acc[1]);
                acc[2] = fmaf(a, bf_lo(v.y), acc[2]); acc[3] = fmaf(a, bf_hi(v.y), acc[3]);
                acc[4] = fmaf(a, bf_lo(v.z), acc[4]); acc[5] = fmaf(a, bf_hi(v.z), acc[5]);
                acc[6] = fmaf(a, bf_lo(v.w), acc[6]); acc[7] = fmaf(a, bf_hi(v.w), acc[7]);
            }
        }
    }
#pragma unroll
    for (int o = 8; o <= 32; o <<= 1)
#pragma unroll
        for (int i = 0; i < 8; i++) acc[i] += __shfl_xor(acc[i], o);
    if (sub == 0) {
        float* op = out + (size_t)node * 64 + cl * 8;
        const float* bp = bias + cl * 8;
#pragma unroll
        for (int i = 0; i < 8; i++) op[i] = fmaxf(acc[i] + bp[i], 0.f);
    }
}

// ---------------- launcher ----------------

extern "C" void kernel_launch(void* const* d_in, const int* in_sizes, int n_in,
                              void* d_out, int out_size, void* d_ws, size_t ws_size,
                              hipStream_t stream) {
    const float* x        = (const float*)d_in[0];
    const int*   ei       = (const int*)d_in[1];   // int32 per harness convention
    const float* W1       = (const float*)d_in[2];
    const float* attS1    = (const float*)d_in[3];
    const float* attD1    = (const float*)d_in[4];
    const float* b1       = (const float*)d_in[5];
    const float* W2       = (const float*)d_in[6];
    const float* attS2    = (const float*)d_in[7];
    const float* attD2    = (const float*)d_in[8];
    const float* b2       = (const float*)d_in[9];
    float* out            = (float*)d_out;

    int N  = in_sizes[0] / 128;
    int E  = in_sizes[1] / 2;
    int EE = E + N;                    // with self-loops
    int K  = (N + NB - 1) >> LOG_NB;   // buckets (98 for N=50000)

    char* w = (char*)d_ws;
    auto alloc = [&](size_t bytes) -> void* {
        void* p = (void*)w;
        w += (bytes + 255) & ~(size_t)255;
        return p;
    };
    int*   bcnt = (int*)alloc((size_t)(K + 1) * 4);
    int*   boff = (int*)alloc((size_t)(K + 1) * 4);
    int*   bcur = (int*)alloc((size_t)(K + 1) * 4);
    int*   off  = (int*)alloc((size_t)(N + 1) * 4);
    unsigned int* csrc = (unsigned int*)alloc((size_t)EE * 4);
    unsigned int* bkt  = (unsigned int*)alloc((size_t)E * 4);           // OWN buffer (no alias!)
    unsigned short* xl1 = (unsigned short*)alloc((size_t)N * 128 * 2);  // bf16; reused as xl2
    float* sd1  = (float*)alloc((size_t)N * 2 * 4);
    float* dd1  = (float*)alloc((size_t)N * 2 * 4);
    float* h1   = (float*)alloc((size_t)N * 128 * 4);                   // fp32

    unsigned short* xl2 = xl1;               // layer-2 xl (bf16), xl1 dead by then
    float* sd2 = sd1;
    float* dd2 = dd1;

    hipMemsetAsync(bcnt, 0, (size_t)(K + 1) * 4, stream);

    int G   = 256;
    int CH  = (E + G - 1) / G;
    int GB1 = (N + 63) / 64;    // gemm1 blocks (ROWS=64)
    sort_count_kernel<<<G, 256, 0, stream>>>(ei, E, K, CH, bcnt);
    sort_scan_kernel<<<1, MAXK, 0, stream>>>(bcnt, boff, bcur, K, E);
    // fused: scatter (blocks [0,G)) + layer-1 GEMM (blocks [G, G+GB1)) — independent work,
    // bkt and xl1 are distinct buffers so concurrent writes are safe.
    scatter_gemm1_kernel<<<G + GB1, 256, 0, stream>>>(ei, E, K, CH, bcur, bkt,
                                                      x, W1, attS1, attD1, xl1, sd1, dd1, N, G);
    sort_finalize_kernel<<<K, 256, 0, stream>>>(bkt, boff, off, csrc, N);

    // ---- layer 1 aggregate ----
    agg1_kernel<<<(N + 3) / 4, 256, 0, stream>>>(xl1, sd1, dd1, b1, off, csrc, h1, N);

    // ---- layer 2 ----
    gemm2_kernel<<<(N + 63) / 64, 256, 0, stream>>>(h1, W2, attS2, attD2, xl2, sd2, dd2, N);
    agg2_kernel<<<(N + 3) / 4, 256, 0, stream>>>(xl2, sd2, dd2, b2, off, csrc, out, N);
}

// Round 15
// 309.996 us; speedup vs baseline: 1.1509x; 1.0293x over previous
//
#include <hip/hip_runtime.h>
#include <cstdint>
#include <cstddef>

#define NEG_SLOPE 0.2f

// Edge packing relies on N <= 65536 (here N = 50000): edge = src | (dst<<16).
// Self-loops are NOT sorted: placed analytically (one per node, first slot).
// csrc[] stores the PACKED edge (src in low 16, dst in high 16).
// NOTE: bkt MUST NOT alias xl1 — scatter and gemm1 run concurrently (fused kernel).
#define NB 128        // nodes per bucket (391 finalize blocks -> fills CUs)
#define LOG_NB 7
#define MAXK 512

__device__ inline unsigned short f2bf(float f) {          // RNE fp32->bf16
    unsigned int u = __float_as_uint(f);
    u += 0x7FFFu + ((u >> 16) & 1u);
    return (unsigned short)(u >> 16);
}
__device__ inline float bf_lo(unsigned int u) { return __uint_as_float(u << 16); }
__device__ inline float bf_hi(unsigned int u) { return __uint_as_float(u & 0xFFFF0000u); }

// ---------------- P1: bucket histogram, 4-way wave-replicated (real edges only) ----------------
__global__ __launch_bounds__(256) void sort_count_kernel(const int* __restrict__ ei, int E,
                                                         int K, int CH, int* __restrict__ bcnt) {
    __shared__ int hist[4 * MAXK];
    int tid = threadIdx.x;
    int wiw = tid >> 6;
    for (int i = tid; i < K; i += 256) {
        hist[i] = 0; hist[MAXK + i] = 0; hist[2 * MAXK + i] = 0; hist[3 * MAXK + i] = 0;
    }
    __syncthreads();
    int lo = blockIdx.x * CH;
    int hi = lo + CH; if (hi > E) hi = E;
    for (int e = lo + tid; e < hi; e += 256)
        atomicAdd(&hist[wiw * MAXK + (ei[(size_t)E + e] >> LOG_NB)], 1);
    __syncthreads();
    for (int i = tid; i < K; i += 256) {
        int c = hist[i] + hist[MAXK + i] + hist[2 * MAXK + i] + hist[3 * MAXK + i];
        if (c) atomicAdd(&bcnt[i], c);
    }
}

// ---------------- P2: scan bucket counts ----------------
__global__ void sort_scan_kernel(const int* __restrict__ bcnt, int* __restrict__ boff,
                                 int* __restrict__ bcur, int K, int E) {
    __shared__ int buf[MAXK];
    int tid = threadIdx.x;   // 512 threads
    int v = (tid < K) ? bcnt[tid] : 0;
    buf[tid] = v;
    __syncthreads();
    for (int o = 1; o < MAXK; o <<= 1) {
        int t = (tid >= o) ? buf[tid - o] : 0;
        __syncthreads();
        buf[tid] += t;
        __syncthreads();
    }
    if (tid < K) {
        int ex = buf[tid] - v;
        boff[tid] = ex;
        bcur[tid] = ex;
    }
    if (tid == K) boff[K] = E;
}

// ---- GEMM + fused att dots body: K-tiles of 32 (low LDS, high occupancy) ----

template <int FOUT, int H, int ROWS>
__device__ __forceinline__ void gemm_att_body(const float* __restrict__ X,
                                              const float* __restrict__ W,
                                              const float* __restrict__ attS,
                                              const float* __restrict__ attD,
                                              unsigned short* __restrict__ Ybf,
                                              float* __restrict__ as_,
                                              float* __restrict__ ad_, int N, int bid,
                                              float* sX, float* sW) {
    constexpr int CG  = FOUT / 4;
    constexpr int RR  = (ROWS * FOUT) / 1024;   // rows per thread
    constexpr int LDX = 36;                     // 32 + 4 pad
    int tid = threadIdx.x;
    int rowbase = bid * ROWS;
    int cg = tid % CG;
    int rg = tid / CG;
    int r0 = rg * RR;

    float acc[RR][4];
#pragma unroll
    for (int i = 0; i < RR; i++)
#pragma unroll
        for (int c = 0; c < 4; c++) acc[i][c] = 0.f;

    for (int k0 = 0; k0 < 128; k0 += 32) {
        __syncthreads();
        for (int idx = tid; idx < ROWS * 8; idx += 256) {
            int r = idx >> 3, q = idx & 7;
            int row = rowbase + r;
            float4 val = (row < N) ? *(const float4*)&X[(size_t)row * 128 + k0 + q * 4]
                                   : make_float4(0.f, 0.f, 0.f, 0.f);
            *(float4*)&sX[r * LDX + q * 4] = val;
        }
        for (int idx = tid; idx < 8 * FOUT; idx += 256)
            *(float4*)&sW[idx * 4] = *(const float4*)&W[(size_t)k0 * FOUT + idx * 4];
        __syncthreads();
        for (int k = 0; k < 32; k += 4) {
            float4 xr[RR];
#pragma unroll
            for (int i = 0; i < RR; i++)
                xr[i] = *(const float4*)&sX[(r0 + i) * LDX + k];
#pragma unroll
            for (int kk = 0; kk < 4; kk++) {
                float4 wv = ((const float4*)(sW + (size_t)(k + kk) * FOUT))[cg];
#pragma unroll
                for (int i = 0; i < RR; i++) {
                    float xv = (&xr[i].x)[kk];
                    acc[i][0] = fmaf(xv, wv.x, acc[i][0]);
                    acc[i][1] = fmaf(xv, wv.y, acc[i][1]);
                    acc[i][2] = fmaf(xv, wv.z, acc[i][2]);
                    acc[i][3] = fmaf(xv, wv.w, acc[i][3]);
                }
            }
        }
    }

    // store bf16 Y
#pragma unroll
    for (int i = 0; i < RR; i++) {
        int row = rowbase + r0 + i;
        if (row < N) {
            ushort4 v;
            v.x = f2bf(acc[i][0]); v.y = f2bf(acc[i][1]);
            v.z = f2bf(acc[i][2]); v.w = f2bf(acc[i][3]);
            *(ushort4*)(Ybf + (size_t)row * FOUT + cg * 4) = v;
        }
    }

    // fused att dots
    float4 asv = ((const float4*)attS)[cg];
    float4 adv = ((const float4*)attD)[cg];
    int head = (H == 2) ? (cg >> 4) : 0;
#pragma unroll
    for (int i = 0; i < RR; i++) {
        float ps = acc[i][0] * asv.x + acc[i][1] * asv.y + acc[i][2] * asv.z + acc[i][3] * asv.w;
        float pd = acc[i][0] * adv.x + acc[i][1] * adv.y + acc[i][2] * adv.z + acc[i][3] * adv.w;
#pragma unroll
        for (int o = 1; o <= 8; o <<= 1) { ps += __shfl_xor(ps, o); pd += __shfl_xor(pd, o); }
        int row = rowbase + r0 + i;
        if ((tid & 15) == 0 && row < N) {
            as_[(size_t)row * H + head] = ps;
            ad_[(size_t)row * H + head] = pd;
        }
    }
}

// ---------------- P3 fused with layer-1 GEMM: blocks [0,G) scatter, rest gemm ----------------
__global__ __launch_bounds__(256) void scatter_gemm1_kernel(const int* __restrict__ ei, int E,
                                                            int K, int CH, int* __restrict__ bcur,
                                                            unsigned int* __restrict__ bkt,
                                                            const float* __restrict__ X,
                                                            const float* __restrict__ W1,
                                                            const float* __restrict__ attS,
                                                            const float* __restrict__ attD,
                                                            unsigned short* __restrict__ Ybf,
                                                            float* __restrict__ as_,
                                                            float* __restrict__ ad_, int N, int G) {
    __shared__ float sX[64 * 36];       // 9.2 KB
    __shared__ float sW[32 * 128];      // 16.4 KB
    if (blockIdx.x < G) {
        int* hist = (int*)sX;           // [4][MAXK] = 8 KB <= 9.2 KB
        int* base = (int*)sW;           // MAXK
        int* cur2 = (int*)sW + MAXK;    // MAXK
        int tid = threadIdx.x;
        int wiw = tid >> 6;
        for (int i = tid; i < K; i += 256) {
            hist[i] = 0; hist[MAXK + i] = 0; hist[2 * MAXK + i] = 0; hist[3 * MAXK + i] = 0;
        }
        __syncthreads();
        int lo = blockIdx.x * CH;
        int hi = lo + CH; if (hi > E) hi = E;
        for (int e = lo + tid; e < hi; e += 256)
            atomicAdd(&hist[wiw * MAXK + (ei[(size_t)E + e] >> LOG_NB)], 1);
        __syncthreads();
        for (int i = tid; i < K; i += 256) {
            int c = hist[i] + hist[MAXK + i] + hist[2 * MAXK + i] + hist[3 * MAXK + i];
            base[i] = c ? atomicAdd(&bcur[i], c) : 0;
            cur2[i] = 0;
        }
        __syncthreads();
        for (int e = lo + tid; e < hi; e += 256) {
            int s = ei[e];
            int d = ei[(size_t)E + e];
            int k = d >> LOG_NB;
            int r = atomicAdd(&cur2[k], 1);
            bkt[(size_t)base[k] + r] = (unsigned int)s | ((unsigned int)d << 16);
        }
    } else {
        gemm_att_body<128, 2, 64>(X, W1, attS, attD, Ybf, as_, ad_, N, blockIdx.x - G, sX, sW);
    }
}

// ---------------- standalone GEMM (layer 2): FOUT=64, ROWS=64, RR=4 ----------------
__global__ __launch_bounds__(256) void gemm2_kernel(const float* __restrict__ X,
                                                    const float* __restrict__ W,
                                                    const float* __restrict__ attS,
                                                    const float* __restrict__ attD,
                                                    unsigned short* __restrict__ Ybf,
                                                    float* __restrict__ as_,
                                                    float* __restrict__ ad_, int N) {
    __shared__ float sX[64 * 36];   // 9.2 KB
    __shared__ float sW[32 * 64];   // 8 KB
    gemm_att_body<64, 1, 64>(X, W, attS, attD, Ybf, as_, ad_, N, blockIdx.x, sX, sW);
}

// ---------------- P4: per-bucket CSR finalize (replicated hist; +1 self slot per node) ----------------
__global__ __launch_bounds__(256) void sort_finalize_kernel(const unsigned int* __restrict__ bkt,
                                                            const int* __restrict__ boff,
                                                            int* __restrict__ off,
                                                            unsigned int* __restrict__ csrc, int N) {
    __shared__ int nhist[4 * NB];
    __shared__ int part[256];
    __shared__ int loff[NB];
    int k = blockIdx.x;
    int tid = threadIdx.x;
    int wiw = tid >> 6;
    int node0 = k << LOG_NB;
    int nh = N - node0; if (nh > NB) nh = NB;
    int beg = boff[k], end = boff[k + 1];
    for (int i = tid; i < NB; i += 256) {
        nhist[i] = 0; nhist[NB + i] = 0; nhist[2 * NB + i] = 0; nhist[3 * NB + i] = 0;
    }
    __syncthreads();
    for (int e = beg + tid; e < end; e += 256)
        atomicAdd(&nhist[wiw * NB + ((bkt[e] >> 16) - node0)], 1);
    __syncthreads();
    int i0 = 2 * tid, i1 = 2 * tid + 1;
    int v0 = (i0 < nh) ? nhist[i0] + nhist[NB + i0] + nhist[2 * NB + i0] + nhist[3 * NB + i0] + 1 : 0;
    int v1 = (i1 < nh) ? nhist[i1] + nhist[NB + i1] + nhist[2 * NB + i1] + nhist[3 * NB + i1] + 1 : 0;
    part[tid] = v0 + v1;
    __syncthreads();
    for (int o = 1; o < 256; o <<= 1) {
        int t = (tid >= o) ? part[tid - o] : 0;
        __syncthreads();
        part[tid] += t;
        __syncthreads();
    }
    int gbase = beg + node0;   // node0 self slots precede this bucket
    int base = gbase + ((tid > 0) ? part[tid - 1] : 0);
    if (i0 < nh) loff[i0] = base;
    if (i1 < nh) loff[i1] = base + v0;
    __syncthreads();
    for (int i = tid; i < nh; i += 256) {
        int node = node0 + i;
        off[node] = loff[i];
        csrc[loff[i]] = (unsigned int)node | ((unsigned int)node << 16);  // self-loop first
        nhist[i] = loff[i] + 1;    // single-copy cursor
    }
    if (node0 + nh == N && tid == 0) off[N] = gbase + part[255];
    __syncthreads();
    for (int e = beg + tid; e < end; e += 256) {
        unsigned int p = bkt[e];
        int pos = atomicAdd(&nhist[(p >> 16) - node0], 1);
        csrc[pos] = p;   // keep packed (src | dst<<16)
    }
}

// ---- slow path helper (deg > 64), one node, 3-pass; scratch is a 64-slot float4 chunk ----
__device__ void agg1_node_slow(const char* xbase, const float* as_, float2 adn,
                               const unsigned int* csrc, int beg, int end,
                               int lane, int sub, int hd1, float4* scratch, float* acc) {
    float m0 = -1e30f, m1 = -1e30f;
    for (int b = beg; b < end; b += 64) {
        int e = b + lane;
        if (e < end) {
            int s = (int)(csrc[e] & 0xFFFFu);
            float2 asv = ((const float2*)as_)[s];
            float t0 = asv.x + adn.x; t0 = t0 > 0.f ? t0 : NEG_SLOPE * t0;
            float t1 = asv.y + adn.y; t1 = t1 > 0.f ? t1 : NEG_SLOPE * t1;
            m0 = fmaxf(m0, t0); m1 = fmaxf(m1, t1);
        }
    }
#pragma unroll
    for (int o = 32; o; o >>= 1) {
        m0 = fmaxf(m0, __shfl_xor(m0, o));
        m1 = fmaxf(m1, __shfl_xor(m1, o));
    }
    float s0 = 0.f, s1 = 0.f;
    for (int b = beg; b < end; b += 64) {
        int e = b + lane;
        if (e < end) {
            int s = (int)(csrc[e] & 0xFFFFu);
            float2 asv = ((const float2*)as_)[s];
            float t0 = asv.x + adn.x; t0 = t0 > 0.f ? t0 : NEG_SLOPE * t0;
            float t1 = asv.y + adn.y; t1 = t1 > 0.f ? t1 : NEG_SLOPE * t1;
            s0 += __expf(t0 - m0); s1 += __expf(t1 - m1);
        }
    }
#pragma unroll
    for (int o = 32; o; o >>= 1) { s0 += __shfl_xor(s0, o); s1 += __shfl_xor(s1, o); }
    float i0 = 1.f / s0, i1 = 1.f / s1;
    for (int b = beg; b < end; b += 64) {
        int cnt = end - b; if (cnt > 64) cnt = 64;
        float p0 = 0.f, p1 = 0.f; int so = 0;
        if (lane < cnt) {
            int s = (int)(csrc[b + lane] & 0xFFFFu);
            so = s << 8;
            float2 asv = ((const float2*)as_)[s];
            float t0 = asv.x + adn.x; t0 = t0 > 0.f ? t0 : NEG_SLOPE * t0;
            float t1 = asv.y + adn.y; t1 = t1 > 0.f ? t1 : NEG_SLOPE * t1;
            p0 = __expf(t0 - m0) * i0; p1 = __expf(t1 - m1) * i1;
        }
        scratch[lane] = make_float4(p0, p1, __int_as_float(so), 0.f);
        int iters = (cnt + 3) >> 2;
#pragma unroll 8
        for (int j = 0; j < iters; j++) {
            float4 q = scratch[j * 4 + sub];
            float a  = hd1 ? q.y : q.x;
            uint4 v  = *(const uint4*)(xbase + __float_as_int(q.z));
            acc[0] = fmaf(a, bf_lo(v.x), acc[0]); acc[1] = fmaf(a, bf_hi(v.x), acc[1]);
            acc[2] = fmaf(a, bf_lo(v.y), acc[2]); acc[3] = fmaf(a, bf_hi(v.y), acc[3]);
            acc[4] = fmaf(a, bf_lo(v.z), acc[4]); acc[5] = fmaf(a, bf_hi(v.z), acc[5]);
            acc[6] = fmaf(a, bf_lo(v.w), acc[6]); acc[7] = fmaf(a, bf_hi(v.w), acc[7]);
        }
    }
}

// ---------------- layer-1 softmax+aggregate: TWO nodes per wave (interleaved chains) ----------------
__global__ __launch_bounds__(256) void agg1_kernel(const unsigned short* __restrict__ xl,
                                                   const float* __restrict__ as_,
                                                   const float* __restrict__ ad_,
                                                   const float* __restrict__ bias,
                                                   const int* __restrict__ off,
                                                   const unsigned int* __restrict__ csrc,
                                                   float* __restrict__ out, int N) {
    __shared__ float4 sps[4][2][64];
    int wiw  = threadIdx.x >> 6;
    int lane = threadIdx.x & 63;
    int wv   = blockIdx.x * 4 + wiw;
    int nodeA = wv * 2;
    if (nodeA >= N) return;
    int nodeB = nodeA + 1;
    bool hasB = nodeB < N;
    int begA = off[nodeA], endA = off[nodeA + 1];
    int degA = endA - begA;
    int begB = endA, degB = 0;
    if (hasB) degB = off[nodeB + 1] - endA;
    float2 adnA = ((const float2*)ad_)[nodeA];
    float2 adnB = hasB ? ((const float2*)ad_)[nodeB] : make_float2(0.f, 0.f);

    int cl  = lane & 15;
    int sub = lane >> 4;
    int hd1 = (cl >> 3) & 1;
    const char* xbase = (const char*)xl + cl * 16;   // + src*256
    float accA[8], accB[8];
#pragma unroll
    for (int i = 0; i < 8; i++) { accA[i] = 0.f; accB[i] = 0.f; }

    if (degA <= 64 && degB <= 64) {
        // both chains issued together
        int soA = 0, soB = 0;
        float tA0 = -1e30f, tA1 = -1e30f, tB0 = -1e30f, tB1 = -1e30f;
        if (lane < degA) {
            int s = (int)(csrc[begA + lane] & 0xFFFFu);
            soA = s << 8;
            float2 a = ((const float2*)as_)[s];
            tA0 = a.x + adnA.x; tA0 = tA0 > 0.f ? tA0 : NEG_SLOPE * tA0;
            tA1 = a.y + adnA.y; tA1 = tA1 > 0.f ? tA1 : NEG_SLOPE * tA1;
        }
        if (lane < degB) {
            int s = (int)(csrc[begB + lane] & 0xFFFFu);
            soB = s << 8;
            float2 a = ((const float2*)as_)[s];
            tB0 = a.x + adnB.x; tB0 = tB0 > 0.f ? tB0 : NEG_SLOPE * tB0;
            tB1 = a.y + adnB.y; tB1 = tB1 > 0.f ? tB1 : NEG_SLOPE * tB1;
        }
        float mA0 = tA0, mA1 = tA1, mB0 = tB0, mB1 = tB1;
#pragma unroll
        for (int o = 32; o; o >>= 1) {
            mA0 = fmaxf(mA0, __shfl_xor(mA0, o)); mA1 = fmaxf(mA1, __shfl_xor(mA1, o));
            mB0 = fmaxf(mB0, __shfl_xor(mB0, o)); mB1 = fmaxf(mB1, __shfl_xor(mB1, o));
        }
        float eA0 = (lane < degA) ? __expf(tA0 - mA0) : 0.f;
        float eA1 = (lane < degA) ? __expf(tA1 - mA1) : 0.f;
        float eB0 = (lane < degB) ? __expf(tB0 - mB0) : 0.f;
        float eB1 = (lane < degB) ? __expf(tB1 - mB1) : 0.f;
        float sA0 = eA0, sA1 = eA1, sB0 = eB0, sB1 = eB1;
#pragma unroll
        for (int o = 32; o; o >>= 1) {
            sA0 += __shfl_xor(sA0, o); sA1 += __shfl_xor(sA1, o);
            sB0 += __shfl_xor(sB0, o); sB1 += __shfl_xor(sB1, o);
        }
        sps[wiw][0][lane] = make_float4(eA0 / sA0, eA1 / sA1, __int_as_float(soA), 0.f);
        sps[wiw][1][lane] = make_float4(hasB ? eB0 / sB0 : 0.f, hasB ? eB1 / sB1 : 0.f,
                                        __int_as_float(soB), 0.f);
        int itersA = (degA + 3) >> 2;
        int itersB = (degB + 3) >> 2;
        int iters = itersA > itersB ? itersA : itersB;
#pragma unroll 4
        for (int j = 0; j < iters; j++) {
            if (j < itersA) {    // wave-uniform
                float4 q = sps[wiw][0][j * 4 + sub];
                float a  = hd1 ? q.y : q.x;
                uint4 v  = *(const uint4*)(xbase + __float_as_int(q.z));
                accA[0] = fmaf(a, bf_lo(v.x), accA[0]); accA[1] = fmaf(a, bf_hi(v.x), accA[1]);
                accA[2] = fmaf(a, bf_lo(v.y), accA[2]); accA[3] = fmaf(a, bf_hi(v.y), accA[3]);
                accA[4] = fmaf(a, bf_lo(v.z), accA[4]); accA[5] = fmaf(a, bf_hi(v.z), accA[5]);
                accA[6] = fmaf(a, bf_lo(v.w), accA[6]); accA[7] = fmaf(a, bf_hi(v.w), accA[7]);
            }
            if (j < itersB) {    // wave-uniform
                float4 q = sps[wiw][1][j * 4 + sub];
                float a  = hd1 ? q.y : q.x;
                uint4 v  = *(const uint4*)(xbase + __float_as_int(q.z));
                accB[0] = fmaf(a, bf_lo(v.x), accB[0]); accB[1] = fmaf(a, bf_hi(v.x), accB[1]);
                accB[2] = fmaf(a, bf_lo(v.y), accB[2]); accB[3] = fmaf(a, bf_hi(v.y), accB[3]);
                accB[4] = fmaf(a, bf_lo(v.z), accB[4]); accB[5] = fmaf(a, bf_hi(v.z), accB[5]);
                accB[6] = fmaf(a, bf_lo(v.w), accB[6]); accB[7] = fmaf(a, bf_hi(v.w), accB[7]);
            }
        }
    } else {
        agg1_node_slow(xbase, as_, adnA, csrc, begA, endA, lane, sub, hd1, sps[wiw][0], accA);
        if (hasB)
            agg1_node_slow(xbase, as_, adnB, csrc, begB, begB + degB, lane, sub, hd1, sps[wiw][1], accB);
    }
#pragma unroll
    for (int o = 16; o <= 32; o <<= 1)
#pragma unroll
        for (int i = 0; i < 8; i++) {
            accA[i] += __shfl_xor(accA[i], o);
            accB[i] += __shfl_xor(accB[i], o);
        }
    if (sub == 0) {
        const float* bp = bias + cl * 8;
        float* opA = out + (size_t)nodeA * 128 + cl * 8;
#pragma unroll
        for (int i = 0; i < 8; i++) opA[i] = fmaxf(accA[i] + bp[i], 0.f);
        if (hasB) {
            float* opB = out + (size_t)nodeB * 128 + cl * 8;
#pragma unroll
            for (int i = 0; i < 8; i++) opB[i] = fmaxf(accB[i] + bp[i], 0.f);
        }
    }
}

// ---- layer-2 slow helper ----
__device__ void agg2_node_slow(const char* xbase, const float* as_, float adn,
                               const unsigned int* csrc, int beg, int end,
                               int lane, int sub, float2* scratch, float* acc) {
    float m = -1e30f;
    for (int b = beg; b < end; b += 64) {
        int e = b + lane;
        if (e < end) {
            float t = as_[csrc[e] & 0xFFFFu] + adn;
            t = t > 0.f ? t : NEG_SLOPE * t;
            m = fmaxf(m, t);
        }
    }
#pragma unroll
    for (int o = 32; o; o >>= 1) m = fmaxf(m, __shfl_xor(m, o));
    float sum = 0.f;
    for (int b = beg; b < end; b += 64) {
        int e = b + lane;
        if (e < end) {
            float t = as_[csrc[e] & 0xFFFFu] + adn;
            t = t > 0.f ? t : NEG_SLOPE * t;
            sum += __expf(t - m);
        }
    }
#pragma unroll
    for (int o = 32; o; o >>= 1) sum += __shfl_xor(sum, o);
    float inv = 1.f / sum;
    for (int b = beg; b < end; b += 64) {
        int cnt = end - b; if (cnt > 64) cnt = 64;
        float p = 0.f; int so = 0;
        if (lane < cnt) {
            int s = (int)(csrc[b + lane] & 0xFFFFu);
            so = s << 7;
            float t = as_[s] + adn;
            t = t > 0.f ? t : NEG_SLOPE * t;
            p = __expf(t - m) * inv;
        }
        scratch[lane] = make_float2(p, __int_as_float(so));
        int iters = (cnt + 7) >> 3;
#pragma unroll 8
        for (int j = 0; j < iters; j++) {
            float2 q = scratch[j * 8 + sub];
            float a  = q.x;
            uint4 v  = *(const uint4*)(xbase + __float_as_int(q.y));
            acc[0] = fmaf(a, bf_lo(v.x), acc[0]); acc[1] = fmaf(a, bf_hi(v.x), acc[1]);
            acc[2] = fmaf(a, bf_lo(v.y), acc[2]); acc[3] = fmaf(a, bf_hi(v.y), acc[3]);
            acc[4] = fmaf(a, bf_lo(v.z), acc[4]); acc[5] = fmaf(a, bf_hi(v.z), acc[5]);
            acc[6] = fmaf(a, bf_lo(v.w), acc[6]); acc[7] = fmaf(a, bf_hi(v.w), acc[7]);
        }
    }
}

// ---------------- layer-2 softmax+aggregate: TWO nodes per wave ----------------
__global__ __launch_bounds__(256) void agg2_kernel(const unsigned short* __restrict__ xl,
                                                   const float* __restrict__ as_,
                                                   const float* __restrict__ ad_,
                                                   const float* __restrict__ bias,
                                                   const int* __restrict__ off,
                                                   const unsigned int* __restrict__ csrc,
                                                   float* __restrict__ out, int N) {
    __shared__ float2 sps[4][2][64];
    int wiw  = threadIdx.x >> 6;
    int lane = threadIdx.x & 63;
    int wv   = blockIdx.x * 4 + wiw;
    int nodeA = wv * 2;
    if (nodeA >= N) return;
    int nodeB = nodeA + 1;
    bool hasB = nodeB < N;
    int begA = off[nodeA], endA = off[nodeA + 1];
    int degA = endA - begA;
    int begB = endA, degB = 0;
    if (hasB) degB = off[nodeB + 1] - endA;
    float adnA = ad_[nodeA];
    float adnB = hasB ? ad_[nodeB] : 0.f;

    int cl  = lane & 7;
    int sub = lane >> 3;
    const char* xbase = (const char*)xl + cl * 16;   // + src*128
    float accA[8], accB[8];
#pragma unroll
    for (int i = 0; i < 8; i++) { accA[i] = 0.f; accB[i] = 0.f; }

    if (degA <= 64 && degB <= 64) {
        int soA = 0, soB = 0;
        float tA = -1e30f, tB = -1e30f;
        if (lane < degA) {
            int s = (int)(csrc[begA + lane] & 0xFFFFu);
            soA = s << 7;
            tA = as_[s] + adnA;
            tA = tA > 0.f ? tA : NEG_SLOPE * tA;
        }
        if (lane < degB) {
            int s = (int)(csrc[begB + lane] & 0xFFFFu);
            soB = s << 7;
            tB = as_[s] + adnB;
            tB = tB > 0.f ? tB : NEG_SLOPE * tB;
        }
        float mA = tA, mB = tB;
#pragma unroll
        for (int o = 32; o; o >>= 1) {
            mA = fmaxf(mA, __shfl_xor(mA, o));
            mB = fmaxf(mB, __shfl_xor(mB, o));
        }
        float eA = (lane < degA) ? __expf(tA - mA) : 0.f;
        float eB = (lane < degB) ? __expf(tB - mB) : 0.f;
        float sA = eA, sB = eB;
#pragma unroll
        for (int o = 32; o; o >>= 1) { sA += __shfl_xor(sA, o); sB += __shfl_xor(sB, o); }
        sps[wiw][0][lane] = make_float2(eA / sA, __int_as_float(soA));
        sps[wiw][1][lane] = make_float2(hasB ? eB / sB : 0.f, __int_as_float(soB));
        int itersA = (degA + 7) >> 3;
        int itersB = (degB + 7) >> 3;
        int iters = itersA > itersB ? itersA : itersB;
#pragma unroll 4
        for (int j = 0; j < iters; j++) {
            if (j < itersA) {
                float2 q = sps[wiw][0][j * 8 + sub];
                float a  = q.x;
                uint4 v  = *(const uint4*)(xbase + __float_as_int(q.y));
                accA[0] = fmaf(a, bf_lo(v.x), accA[0]); accA[1] = fmaf(a, bf_hi(v.x), accA[1]);
                accA[2] = fmaf(a, bf_lo(v.y), accA[2]); accA[3] = fmaf(a, bf_hi(v.y), accA[3]);
                accA[4] = fmaf(a, bf_lo(v.z), accA[4]); accA[5] = fmaf(a, bf_hi(v.z), accA[5]);
                accA[6] = fmaf(a, bf_lo(v.w), accA[6]); accA[7] = fmaf(a, bf_hi(v.w), accA[7]);
            }
            if (j < itersB) {
                float2 q = sps[wiw][1][j * 8 + sub];
                float a  = q.x;
                uint4 v  = *(const uint4*)(xbase + __float_as_int(q.y));
                accB[0] = fmaf(a, bf_lo(v.x), accB[0]); accB[1] = fmaf(a, bf_hi(v.x), accB[1]);
                accB[2] = fmaf(a, bf_lo(v.y), accB[2]); accB[3] = fmaf(a, bf_hi(v.y), accB[3]);
                accB[4] = fmaf(a, bf_lo(v.z), accB[4]); accB[5] = fmaf(a, bf_hi(v.z), accB[5]);
                accB[6] = fmaf(a, bf_lo(v.w), accB[6]); accB[7] = fmaf(a, bf_hi(v.w), accB[7]);
            }
        }
    } else {
        agg2_node_slow(xbase, as_, adnA, csrc, begA, endA, lane, sub, sps[wiw][0], accA);
        if (hasB)
            agg2_node_slow(xbase, as_, adnB, csrc, begB, begB + degB, lane, sub, sps[wiw][1], accB);
    }
#pragma unroll
    for (int o = 8; o <= 32; o <<= 1)
#pragma unroll
        for (int i = 0; i < 8; i++) {
            accA[i] += __shfl_xor(accA[i], o);
            accB[i] += __shfl_xor(accB[i], o);
        }
    if (sub == 0) {
        const float* bp = bias + cl * 8;
        float* opA = out + (size_t)nodeA * 64 + cl * 8;
#pragma unroll
        for (int i = 0; i < 8; i++) opA[i] = fmaxf(accA[i] + bp[i], 0.f);
        if (hasB) {
            float* opB = out + (size_t)nodeB * 64 + cl * 8;
#pragma unroll
            for (int i = 0; i < 8; i++) opB[i] = fmaxf(accB[i] + bp[i], 0.f);
        }
    }
}

// ---------------- launcher ----------------

extern "C" void kernel_launch(void* const* d_in, const int* in_sizes, int n_in,
                              void* d_out, int out_size, void* d_ws, size_t ws_size,
                              hipStream_t stream) {
    const float* x        = (const float*)d_in[0];
    const int*   ei       = (const int*)d_in[1];   // int32 per harness convention
    const float* W1       = (const float*)d_in[2];
    const float* attS1    = (const float*)d_in[3];
    const float* attD1    = (const float*)d_in[4];
    const float* b1       = (const float*)d_in[5];
    const float* W2       = (const float*)d_in[6];
    const float* attS2    = (const float*)d_in[7];
    const float* attD2    = (const float*)d_in[8];
    const float* b2       = (const float*)d_in[9];
    float* out            = (float*)d_out;

    int N  = in_sizes[0] / 128;
    int E  = in_sizes[1] / 2;
    int EE = E + N;                    // with self-loops
    int K  = (N + NB - 1) >> LOG_NB;   // buckets (391 for N=50000)

    char* w = (char*)d_ws;
    auto alloc = [&](size_t bytes) -> void* {
        void* p = (void*)w;
        w += (bytes + 255) & ~(size_t)255;
        return p;
    };
    int*   bcnt = (int*)alloc((size_t)(K + 1) * 4);
    int*   boff = (int*)alloc((size_t)(K + 1) * 4);
    int*   bcur = (int*)alloc((size_t)(K + 1) * 4);
    int*   off  = (int*)alloc((size_t)(N + 1) * 4);
    unsigned int* csrc = (unsigned int*)alloc((size_t)EE * 4);
    unsigned int* bkt  = (unsigned int*)alloc((size_t)E * 4);           // OWN buffer (no alias!)
    unsigned short* xl1 = (unsigned short*)alloc((size_t)N * 128 * 2);  // bf16; reused as xl2
    float* sd1  = (float*)alloc((size_t)N * 2 * 4);
    float* dd1  = (float*)alloc((size_t)N * 2 * 4);
    float* h1   = (float*)alloc((size_t)N * 128 * 4);                   // fp32

    unsigned short* xl2 = xl1;               // layer-2 xl (bf16), xl1 dead by then
    float* sd2 = sd1;
    float* dd2 = dd1;

    hipMemsetAsync(bcnt, 0, (size_t)(K + 1) * 4, stream);

    int G   = 256;
    int CH  = (E + G - 1) / G;
    int GB1 = (N + 63) / 64;    // gemm1 blocks (ROWS=64)
    sort_count_kernel<<<G, 256, 0, stream>>>(ei, E, K, CH, bcnt);
    sort_scan_kernel<<<1, MAXK, 0, stream>>>(bcnt, boff, bcur, K, E);
    // fused: scatter (blocks [0,G)) + layer-1 GEMM (blocks [G, G+GB1)) — independent work,
    // bkt and xl1 are distinct buffers so concurrent writes are safe.
    scatter_gemm1_kernel<<<G + GB1, 256, 0, stream>>>(ei, E, K, CH, bcur, bkt,
                                                      x, W1, attS1, attD1, xl1, sd1, dd1, N, G);
    sort_finalize_kernel<<<K, 256, 0, stream>>>(bkt, boff, off, csrc, N);

    // ---- layer 1 aggregate (2 nodes/wave) ----
    agg1_kernel<<<(N + 7) / 8, 256, 0, stream>>>(xl1, sd1, dd1, b1, off, csrc, h1, N);

    // ---- layer 2 ----
    gemm2_kernel<<<(N + 63) / 64, 256, 0, stream>>>(h1, W2, attS2, attD2, xl2, sd2, dd2, N);
    agg2_kernel<<<(N + 7) / 8, 256, 0, stream>>>(xl2, sd2, dd2, b2, off, csrc, out, N);
}

// Round 16
// 293.600 us; speedup vs baseline: 1.2151x; 1.0558x over previous
//
#include <hip/hip_runtime.h>
#include <cstdint>
#include <cstddef>

#define NEG_SLOPE 0.2f

// Edge packing relies on N <= 65536 (here N = 50000): edge = src | (dst<<16).
// Self-loops are NOT sorted: placed analytically (one per node, first slot).
// csrc[] stores the PACKED edge (src in low 16, dst in high 16).
// NOTE: bkt MUST NOT alias xl1 — scatter and gemm1 run concurrently (fused kernel).
#define NB 128        // nodes per bucket (391 finalize blocks -> fills CUs)
#define LOG_NB 7
#define MAXK 512

__device__ inline unsigned short f2bf(float f) {          // RNE fp32->bf16
    unsigned int u = __float_as_uint(f);
    u += 0x7FFFu + ((u >> 16) & 1u);
    return (unsigned short)(u >> 16);
}
__device__ inline float bf_lo(unsigned int u) { return __uint_as_float(u << 16); }
__device__ inline float bf_hi(unsigned int u) { return __uint_as_float(u & 0xFFFF0000u); }

// ---------------- P1: bucket histogram, 4-way wave-replicated (real edges only) ----------------
__global__ __launch_bounds__(256) void sort_count_kernel(const int* __restrict__ ei, int E,
                                                         int K, int CH, int* __restrict__ bcnt) {
    __shared__ int hist[4 * MAXK];
    int tid = threadIdx.x;
    int wiw = tid >> 6;
    for (int i = tid; i < K; i += 256) {
        hist[i] = 0; hist[MAXK + i] = 0; hist[2 * MAXK + i] = 0; hist[3 * MAXK + i] = 0;
    }
    __syncthreads();
    int lo = blockIdx.x * CH;
    int hi = lo + CH; if (hi > E) hi = E;
    for (int e = lo + tid; e < hi; e += 256)
        atomicAdd(&hist[wiw * MAXK + (ei[(size_t)E + e] >> LOG_NB)], 1);
    __syncthreads();
    for (int i = tid; i < K; i += 256) {
        int c = hist[i] + hist[MAXK + i] + hist[2 * MAXK + i] + hist[3 * MAXK + i];
        if (c) atomicAdd(&bcnt[i], c);
    }
}

// ---------------- P2: scan bucket counts ----------------
__global__ void sort_scan_kernel(const int* __restrict__ bcnt, int* __restrict__ boff,
                                 int* __restrict__ bcur, int K, int E) {
    __shared__ int buf[MAXK];
    int tid = threadIdx.x;   // 512 threads
    int v = (tid < K) ? bcnt[tid] : 0;
    buf[tid] = v;
    __syncthreads();
    for (int o = 1; o < MAXK; o <<= 1) {
        int t = (tid >= o) ? buf[tid - o] : 0;
        __syncthreads();
        buf[tid] += t;
        __syncthreads();
    }
    if (tid < K) {
        int ex = buf[tid] - v;
        boff[tid] = ex;
        bcur[tid] = ex;
    }
    if (tid == K) boff[K] = E;
}

// ---- GEMM + fused att dots body: K-tiles of 32 (low LDS, high occupancy) ----

template <int FOUT, int H, int ROWS>
__device__ __forceinline__ void gemm_att_body(const float* __restrict__ X,
                                              const float* __restrict__ W,
                                              const float* __restrict__ attS,
                                              const float* __restrict__ attD,
                                              unsigned short* __restrict__ Ybf,
                                              float* __restrict__ as_,
                                              float* __restrict__ ad_, int N, int bid,
                                              float* sX, float* sW) {
    constexpr int CG  = FOUT / 4;
    constexpr int RR  = (ROWS * FOUT) / 1024;   // rows per thread
    constexpr int LDX = 36;                     // 32 + 4 pad
    int tid = threadIdx.x;
    int rowbase = bid * ROWS;
    int cg = tid % CG;
    int rg = tid / CG;
    int r0 = rg * RR;

    float acc[RR][4];
#pragma unroll
    for (int i = 0; i < RR; i++)
#pragma unroll
        for (int c = 0; c < 4; c++) acc[i][c] = 0.f;

    for (int k0 = 0; k0 < 128; k0 += 32) {
        __syncthreads();
        for (int idx = tid; idx < ROWS * 8; idx += 256) {
            int r = idx >> 3, q = idx & 7;
            int row = rowbase + r;
            float4 val = (row < N) ? *(const float4*)&X[(size_t)row * 128 + k0 + q * 4]
                                   : make_float4(0.f, 0.f, 0.f, 0.f);
            *(float4*)&sX[r * LDX + q * 4] = val;
        }
        for (int idx = tid; idx < 8 * FOUT; idx += 256)
            *(float4*)&sW[idx * 4] = *(const float4*)&W[(size_t)k0 * FOUT + idx * 4];
        __syncthreads();
        for (int k = 0; k < 32; k += 4) {
            float4 xr[RR];
#pragma unroll
            for (int i = 0; i < RR; i++)
                xr[i] = *(const float4*)&sX[(r0 + i) * LDX + k];
#pragma unroll
            for (int kk = 0; kk < 4; kk++) {
                float4 wv = ((const float4*)(sW + (size_t)(k + kk) * FOUT))[cg];
#pragma unroll
                for (int i = 0; i < RR; i++) {
                    float xv = (&xr[i].x)[kk];
                    acc[i][0] = fmaf(xv, wv.x, acc[i][0]);
                    acc[i][1] = fmaf(xv, wv.y, acc[i][1]);
                    acc[i][2] = fmaf(xv, wv.z, acc[i][2]);
                    acc[i][3] = fmaf(xv, wv.w, acc[i][3]);
                }
            }
        }
    }

    // store bf16 Y
#pragma unroll
    for (int i = 0; i < RR; i++) {
        int row = rowbase + r0 + i;
        if (row < N) {
            ushort4 v;
            v.x = f2bf(acc[i][0]); v.y = f2bf(acc[i][1]);
            v.z = f2bf(acc[i][2]); v.w = f2bf(acc[i][3]);
            *(ushort4*)(Ybf + (size_t)row * FOUT + cg * 4) = v;
        }
    }

    // fused att dots
    float4 asv = ((const float4*)attS)[cg];
    float4 adv = ((const float4*)attD)[cg];
    int head = (H == 2) ? (cg >> 4) : 0;
#pragma unroll
    for (int i = 0; i < RR; i++) {
        float ps = acc[i][0] * asv.x + acc[i][1] * asv.y + acc[i][2] * asv.z + acc[i][3] * asv.w;
        float pd = acc[i][0] * adv.x + acc[i][1] * adv.y + acc[i][2] * adv.z + acc[i][3] * adv.w;
#pragma unroll
        for (int o = 1; o <= 8; o <<= 1) { ps += __shfl_xor(ps, o); pd += __shfl_xor(pd, o); }
        int row = rowbase + r0 + i;
        if ((tid & 15) == 0 && row < N) {
            as_[(size_t)row * H + head] = ps;
            ad_[(size_t)row * H + head] = pd;
        }
    }
}

// ---------------- P3 fused with layer-1 GEMM: blocks [0,G) scatter, rest gemm ----------------
__global__ __launch_bounds__(256) void scatter_gemm1_kernel(const int* __restrict__ ei, int E,
                                                            int K, int CH, int* __restrict__ bcur,
                                                            unsigned int* __restrict__ bkt,
                                                            const float* __restrict__ X,
                                                            const float* __restrict__ W1,
                                                            const float* __restrict__ attS,
                                                            const float* __restrict__ attD,
                                                            unsigned short* __restrict__ Ybf,
                                                            float* __restrict__ as_,
                                                            float* __restrict__ ad_, int N, int G) {
    __shared__ float sX[64 * 36];       // 9.2 KB
    __shared__ float sW[32 * 128];      // 16.4 KB
    if (blockIdx.x < G) {
        int* hist = (int*)sX;           // [4][MAXK] = 8 KB <= 9.2 KB
        int* base = (int*)sW;           // MAXK
        int* cur2 = (int*)sW + MAXK;    // MAXK
        int tid = threadIdx.x;
        int wiw = tid >> 6;
        for (int i = tid; i < K; i += 256) {
            hist[i] = 0; hist[MAXK + i] = 0; hist[2 * MAXK + i] = 0; hist[3 * MAXK + i] = 0;
        }
        __syncthreads();
        int lo = blockIdx.x * CH;
        int hi = lo + CH; if (hi > E) hi = E;
        for (int e = lo + tid; e < hi; e += 256)
            atomicAdd(&hist[wiw * MAXK + (ei[(size_t)E + e] >> LOG_NB)], 1);
        __syncthreads();
        for (int i = tid; i < K; i += 256) {
            int c = hist[i] + hist[MAXK + i] + hist[2 * MAXK + i] + hist[3 * MAXK + i];
            base[i] = c ? atomicAdd(&bcur[i], c) : 0;
            cur2[i] = 0;
        }
        __syncthreads();
        for (int e = lo + tid; e < hi; e += 256) {
            int s = ei[e];
            int d = ei[(size_t)E + e];
            int k = d >> LOG_NB;
            int r = atomicAdd(&cur2[k], 1);
            bkt[(size_t)base[k] + r] = (unsigned int)s | ((unsigned int)d << 16);
        }
    } else {
        gemm_att_body<128, 2, 64>(X, W1, attS, attD, Ybf, as_, ad_, N, blockIdx.x - G, sX, sW);
    }
}

// ---------------- standalone GEMM (layer 2): FOUT=64, ROWS=64, RR=4 ----------------
__global__ __launch_bounds__(256) void gemm2_kernel(const float* __restrict__ X,
                                                    const float* __restrict__ W,
                                                    const float* __restrict__ attS,
                                                    const float* __restrict__ attD,
                                                    unsigned short* __restrict__ Ybf,
                                                    float* __restrict__ as_,
                                                    float* __restrict__ ad_, int N) {
    __shared__ float sX[64 * 36];   // 9.2 KB
    __shared__ float sW[32 * 64];   // 8 KB
    gemm_att_body<64, 1, 64>(X, W, attS, attD, Ybf, as_, ad_, N, blockIdx.x, sX, sW);
}

// ---------------- P4: per-bucket CSR finalize (replicated hist; +1 self slot per node) ----------------
__global__ __launch_bounds__(256) void sort_finalize_kernel(const unsigned int* __restrict__ bkt,
                                                            const int* __restrict__ boff,
                                                            int* __restrict__ off,
                                                            unsigned int* __restrict__ csrc, int N) {
    __shared__ int nhist[4 * NB];
    __shared__ int part[256];
    __shared__ int loff[NB];
    int k = blockIdx.x;
    int tid = threadIdx.x;
    int wiw = tid >> 6;
    int node0 = k << LOG_NB;
    int nh = N - node0; if (nh > NB) nh = NB;
    int beg = boff[k], end = boff[k + 1];
    for (int i = tid; i < NB; i += 256) {
        nhist[i] = 0; nhist[NB + i] = 0; nhist[2 * NB + i] = 0; nhist[3 * NB + i] = 0;
    }
    __syncthreads();
    for (int e = beg + tid; e < end; e += 256)
        atomicAdd(&nhist[wiw * NB + ((bkt[e] >> 16) - node0)], 1);
    __syncthreads();
    int i0 = 2 * tid, i1 = 2 * tid + 1;
    int v0 = (i0 < nh) ? nhist[i0] + nhist[NB + i0] + nhist[2 * NB + i0] + nhist[3 * NB + i0] + 1 : 0;
    int v1 = (i1 < nh) ? nhist[i1] + nhist[NB + i1] + nhist[2 * NB + i1] + nhist[3 * NB + i1] + 1 : 0;
    part[tid] = v0 + v1;
    __syncthreads();
    for (int o = 1; o < 256; o <<= 1) {
        int t = (tid >= o) ? part[tid - o] : 0;
        __syncthreads();
        part[tid] += t;
        __syncthreads();
    }
    int gbase = beg + node0;   // node0 self slots precede this bucket
    int base = gbase + ((tid > 0) ? part[tid - 1] : 0);
    if (i0 < nh) loff[i0] = base;
    if (i1 < nh) loff[i1] = base + v0;
    __syncthreads();
    for (int i = tid; i < nh; i += 256) {
        int node = node0 + i;
        off[node] = loff[i];
        csrc[loff[i]] = (unsigned int)node | ((unsigned int)node << 16);  // self-loop first
        nhist[i] = loff[i] + 1;    // single-copy cursor
    }
    if (node0 + nh == N && tid == 0) off[N] = gbase + part[255];
    __syncthreads();
    for (int e = beg + tid; e < end; e += 256) {
        unsigned int p = bkt[e];
        int pos = atomicAdd(&nhist[(p >> 16) - node0], 1);
        csrc[pos] = p;   // keep packed (src | dst<<16)
    }
}

// ---------------- layer-1 softmax+aggregate: one wave per NODE, both heads ----------------
// (r13/r14-measured best: 70.5 µs, 56 VGPR, 4 KB LDS, 50K waves)

__global__ __launch_bounds__(256) void agg1_kernel(const unsigned short* __restrict__ xl,
                                                   const float* __restrict__ as_,
                                                   const float* __restrict__ ad_,
                                                   const float* __restrict__ bias,
                                                   const int* __restrict__ off,
                                                   const unsigned int* __restrict__ csrc,
                                                   float* __restrict__ out, int N) {
    __shared__ float4 sps[4][64];   // {p0, p1, as_int(byteoff), -}
    int wiw  = threadIdx.x >> 6;
    int lane = threadIdx.x & 63;
    int node = blockIdx.x * 4 + wiw;
    if (node >= N) return;
    int beg = off[node], end = off[node + 1];
    int deg = end - beg;
    float2 adn = ((const float2*)ad_)[node];

    int cl  = lane & 15;
    int sub = lane >> 4;
    int hd1 = (cl >> 3) & 1;
    float acc[8];
#pragma unroll
    for (int i = 0; i < 8; i++) acc[i] = 0.f;
    const char* xbase = (const char*)xl + cl * 16;   // + src*256

    if (deg <= 64) {
        int so = 0;
        float t0 = -1e30f, t1 = -1e30f;
        if (lane < deg) {
            int s = (int)(csrc[beg + lane] & 0xFFFFu);
            so = s << 8;                       // byte offset of row
            float2 asv = ((const float2*)as_)[s];
            t0 = asv.x + adn.x; t0 = t0 > 0.f ? t0 : NEG_SLOPE * t0;
            t1 = asv.y + adn.y; t1 = t1 > 0.f ? t1 : NEG_SLOPE * t1;
        }
        float m0 = t0, m1 = t1;
#pragma unroll
        for (int o = 32; o; o >>= 1) {
            m0 = fmaxf(m0, __shfl_xor(m0, o));
            m1 = fmaxf(m1, __shfl_xor(m1, o));
        }
        float e0 = (lane < deg) ? __expf(t0 - m0) : 0.f;
        float e1 = (lane < deg) ? __expf(t1 - m1) : 0.f;
        float s0 = e0, s1 = e1;
#pragma unroll
        for (int o = 32; o; o >>= 1) { s0 += __shfl_xor(s0, o); s1 += __shfl_xor(s1, o); }
        sps[wiw][lane] = make_float4(e0 / s0, e1 / s1, __int_as_float(so), 0.f);
        int iters = (deg + 3) >> 2;
#pragma unroll 8
        for (int j = 0; j < iters; j++) {
            float4 q = sps[wiw][j * 4 + sub];
            float a  = hd1 ? q.y : q.x;
            uint4 v  = *(const uint4*)(xbase + __float_as_int(q.z));
            acc[0] = fmaf(a, bf_lo(v.x), acc[0]); acc[1] = fmaf(a, bf_hi(v.x), acc[1]);
            acc[2] = fmaf(a, bf_lo(v.y), acc[2]); acc[3] = fmaf(a, bf_hi(v.y), acc[3]);
            acc[4] = fmaf(a, bf_lo(v.z), acc[4]); acc[5] = fmaf(a, bf_hi(v.z), acc[5]);
            acc[6] = fmaf(a, bf_lo(v.w), acc[6]); acc[7] = fmaf(a, bf_hi(v.w), acc[7]);
        }
    } else {
        // 3-pass fallback (deg > 64)
        float m0 = -1e30f, m1 = -1e30f;
        for (int b = beg; b < end; b += 64) {
            int e = b + lane;
            if (e < end) {
                int s = (int)(csrc[e] & 0xFFFFu);
                float2 asv = ((const float2*)as_)[s];
                float t0 = asv.x + adn.x; t0 = t0 > 0.f ? t0 : NEG_SLOPE * t0;
                float t1 = asv.y + adn.y; t1 = t1 > 0.f ? t1 : NEG_SLOPE * t1;
                m0 = fmaxf(m0, t0); m1 = fmaxf(m1, t1);
            }
        }
#pragma unroll
        for (int o = 32; o; o >>= 1) {
            m0 = fmaxf(m0, __shfl_xor(m0, o));
            m1 = fmaxf(m1, __shfl_xor(m1, o));
        }
        float s0 = 0.f, s1 = 0.f;
        for (int b = beg; b < end; b += 64) {
            int e = b + lane;
            if (e < end) {
                int s = (int)(csrc[e] & 0xFFFFu);
                float2 asv = ((const float2*)as_)[s];
                float t0 = asv.x + adn.x; t0 = t0 > 0.f ? t0 : NEG_SLOPE * t0;
                float t1 = asv.y + adn.y; t1 = t1 > 0.f ? t1 : NEG_SLOPE * t1;
                s0 += __expf(t0 - m0); s1 += __expf(t1 - m1);
            }
        }
#pragma unroll
        for (int o = 32; o; o >>= 1) { s0 += __shfl_xor(s0, o); s1 += __shfl_xor(s1, o); }
        float i0 = 1.f / s0, i1 = 1.f / s1;
        for (int b = beg; b < end; b += 64) {
            int cnt = end - b; if (cnt > 64) cnt = 64;
            float p0 = 0.f, p1 = 0.f; int so = 0;
            if (lane < cnt) {
                int s = (int)(csrc[b + lane] & 0xFFFFu);
                so = s << 8;
                float2 asv = ((const float2*)as_)[s];
                float t0 = asv.x + adn.x; t0 = t0 > 0.f ? t0 : NEG_SLOPE * t0;
                float t1 = asv.y + adn.y; t1 = t1 > 0.f ? t1 : NEG_SLOPE * t1;
                p0 = __expf(t0 - m0) * i0; p1 = __expf(t1 - m1) * i1;
            }
            sps[wiw][lane] = make_float4(p0, p1, __int_as_float(so), 0.f);
            int iters = (cnt + 3) >> 2;
#pragma unroll 8
            for (int j = 0; j < iters; j++) {
                float4 q = sps[wiw][j * 4 + sub];
                float a  = hd1 ? q.y : q.x;
                uint4 v  = *(const uint4*)(xbase + __float_as_int(q.z));
                acc[0] = fmaf(a, bf_lo(v.x), acc[0]); acc[1] = fmaf(a, bf_hi(v.x), acc[1]);
                acc[2] = fmaf(a, bf_lo(v.y), acc[2]); acc[3] = fmaf(a, bf_hi(v.y), acc[3]);
                acc[4] = fmaf(a, bf_lo(v.z), acc[4]); acc[5] = fmaf(a, bf_hi(v.z), acc[5]);
                acc[6] = fmaf(a, bf_lo(v.w), acc[6]); acc[7] = fmaf(a, bf_hi(v.w), acc[7]);
            }
        }
    }
#pragma unroll
    for (int o = 16; o <= 32; o <<= 1)
#pragma unroll
        for (int i = 0; i < 8; i++) acc[i] += __shfl_xor(acc[i], o);
    if (sub == 0) {
        float* op = out + (size_t)node * 128 + cl * 8;
        const float* bp = bias + cl * 8;
#pragma unroll
        for (int i = 0; i < 8; i++) op[i] = fmaxf(acc[i] + bp[i], 0.f);
    }
}

// ---------------- layer-2 softmax+aggregate: one wave per node, H=1, fp32 out ----------------

__global__ __launch_bounds__(256) void agg2_kernel(const unsigned short* __restrict__ xl,
                                                   const float* __restrict__ as_,
                                                   const float* __restrict__ ad_,
                                                   const float* __restrict__ bias,
                                                   const int* __restrict__ off,
                                                   const unsigned int* __restrict__ csrc,
                                                   float* __restrict__ out, int N) {
    __shared__ float2 sps[4][64];   // {p, as_int(byteoff)}
    int wiw  = threadIdx.x >> 6;
    int lane = threadIdx.x & 63;
    int node = blockIdx.x * 4 + wiw;
    if (node >= N) return;
    int beg = off[node], end = off[node + 1];
    int deg = end - beg;
    float adn = ad_[node];

    int cl  = lane & 7;
    int sub = lane >> 3;
    float acc[8];
#pragma unroll
    for (int i = 0; i < 8; i++) acc[i] = 0.f;
    const char* xbase = (const char*)xl + cl * 16;   // + src*128

    if (deg <= 64) {
        int so = 0;
        float t = -1e30f;
        if (lane < deg) {
            int s = (int)(csrc[beg + lane] & 0xFFFFu);
            so = s << 7;
            t = as_[s] + adn;
            t = t > 0.f ? t : NEG_SLOPE * t;
        }
        float m = t;
#pragma unroll
        for (int o = 32; o; o >>= 1) m = fmaxf(m, __shfl_xor(m, o));
        float evv = (lane < deg) ? __expf(t - m) : 0.f;
        float sum = evv;
#pragma unroll
        for (int o = 32; o; o >>= 1) sum += __shfl_xor(sum, o);
        sps[wiw][lane] = make_float2(evv / sum, __int_as_float(so));
        int iters = (deg + 7) >> 3;
#pragma unroll 8
        for (int j = 0; j < iters; j++) {
            float2 q = sps[wiw][j * 8 + sub];
            float a  = q.x;
            uint4 v  = *(const uint4*)(xbase + __float_as_int(q.y));
            acc[0] = fmaf(a, bf_lo(v.x), acc[0]); acc[1] = fmaf(a, bf_hi(v.x), acc[1]);
            acc[2] = fmaf(a, bf_lo(v.y), acc[2]); acc[3] = fmaf(a, bf_hi(v.y), acc[3]);
            acc[4] = fmaf(a, bf_lo(v.z), acc[4]); acc[5] = fmaf(a, bf_hi(v.z), acc[5]);
            acc[6] = fmaf(a, bf_lo(v.w), acc[6]); acc[7] = fmaf(a, bf_hi(v.w), acc[7]);
        }
    } else {
        float m = -1e30f;
        for (int b = beg; b < end; b += 64) {
            int e = b + lane;
            if (e < end) {
                float t = as_[csrc[e] & 0xFFFFu] + adn;
                t = t > 0.f ? t : NEG_SLOPE * t;
                m = fmaxf(m, t);
            }
        }
#pragma unroll
        for (int o = 32; o; o >>= 1) m = fmaxf(m, __shfl_xor(m, o));
        float sum = 0.f;
        for (int b = beg; b < end; b += 64) {
            int e = b + lane;
            if (e < end) {
                float t = as_[csrc[e] & 0xFFFFu] + adn;
                t = t > 0.f ? t : NEG_SLOPE * t;
                sum += __expf(t - m);
            }
        }
#pragma unroll
        for (int o = 32; o; o >>= 1) sum += __shfl_xor(sum, o);
        float inv = 1.f / sum;
        for (int b = beg; b < end; b += 64) {
            int cnt = end - b; if (cnt > 64) cnt = 64;
            float p = 0.f; int so = 0;
            if (lane < cnt) {
                int s = (int)(csrc[b + lane] & 0xFFFFu);
                so = s << 7;
                float t = as_[s] + adn;
                t = t > 0.f ? t : NEG_SLOPE * t;
                p = __expf(t - m) * inv;
            }
            sps[wiw][lane] = make_float2(p, __int_as_float(so));
            int iters = (cnt + 7) >> 3;
#pragma unroll 8
            for (int j = 0; j < iters; j++) {
                float2 q = sps[wiw][j * 8 + sub];
                float a  = q.x;
                uint4 v  = *(const uint4*)(xbase + __float_as_int(q.y));
                acc[0] = fmaf(a, bf_lo(v.x), acc[0]); acc[1] = fmaf(a, bf_hi(v.x), acc[1]);
                acc[2] = fmaf(a, bf_lo(v.y), acc[2]); acc[3] = fmaf(a, bf_hi(v.y), acc[3]);
                acc[4] = fmaf(a, bf_lo(v.z), acc[4]); acc[5] = fmaf(a, bf_hi(v.z), acc[5]);
                acc[6] = fmaf(a, bf_lo(v.w), acc[6]); acc[7] = fmaf(a, bf_hi(v.w), acc[7]);
            }
        }
    }
#pragma unroll
    for (int o = 8; o <= 32; o <<= 1)
#pragma unroll
        for (int i = 0; i < 8; i++) acc[i] += __shfl_xor(acc[i], o);
    if (sub == 0) {
        float* op = out + (size_t)node * 64 + cl * 8;
        const float* bp = bias + cl * 8;
#pragma unroll
        for (int i = 0; i < 8; i++) op[i] = fmaxf(acc[i] + bp[i], 0.f);
    }
}

// ---------------- launcher ----------------

extern "C" void kernel_launch(void* const* d_in, const int* in_sizes, int n_in,
                              void* d_out, int out_size, void* d_ws, size_t ws_size,
                              hipStream_t stream) {
    const float* x        = (const float*)d_in[0];
    const int*   ei       = (const int*)d_in[1];   // int32 per harness convention
    const float* W1       = (const float*)d_in[2];
    const float* attS1    = (const float*)d_in[3];
    const float* attD1    = (const float*)d_in[4];
    const float* b1       = (const float*)d_in[5];
    const float* W2       = (const float*)d_in[6];
    const float* attS2    = (const float*)d_in[7];
    const float* attD2    = (const float*)d_in[8];
    const float* b2       = (const float*)d_in[9];
    float* out            = (float*)d_out;

    int N  = in_sizes[0] / 128;
    int E  = in_sizes[1] / 2;
    int EE = E + N;                    // with self-loops
    int K  = (N + NB - 1) >> LOG_NB;   // buckets (391 for N=50000)

    char* w = (char*)d_ws;
    auto alloc = [&](size_t bytes) -> void* {
        void* p = (void*)w;
        w += (bytes + 255) & ~(size_t)255;
        return p;
    };
    int*   bcnt = (int*)alloc((size_t)(K + 1) * 4);
    int*   boff = (int*)alloc((size_t)(K + 1) * 4);
    int*   bcur = (int*)alloc((size_t)(K + 1) * 4);
    int*   off  = (int*)alloc((size_t)(N + 1) * 4);
    unsigned int* csrc = (unsigned int*)alloc((size_t)EE * 4);
    unsigned int* bkt  = (unsigned int*)alloc((size_t)E * 4);           // OWN buffer (no alias!)
    unsigned short* xl1 = (unsigned short*)alloc((size_t)N * 128 * 2);  // bf16; reused as xl2
    float* sd1  = (float*)alloc((size_t)N * 2 * 4);
    float* dd1  = (float*)alloc((size_t)N * 2 * 4);
    float* h1   = (float*)alloc((size_t)N * 128 * 4);                   // fp32

    unsigned short* xl2 = xl1;               // layer-2 xl (bf16), xl1 dead by then
    float* sd2 = sd1;
    float* dd2 = dd1;

    hipMemsetAsync(bcnt, 0, (size_t)(K + 1) * 4, stream);

    int G   = 256;
    int CH  = (E + G - 1) / G;
    int GB1 = (N + 63) / 64;    // gemm1 blocks (ROWS=64)
    sort_count_kernel<<<G, 256, 0, stream>>>(ei, E, K, CH, bcnt);
    sort_scan_kernel<<<1, MAXK, 0, stream>>>(bcnt, boff, bcur, K, E);
    // fused: scatter (blocks [0,G)) + layer-1 GEMM (blocks [G, G+GB1)) — independent work,
    // bkt and xl1 are distinct buffers so concurrent writes are safe.
    scatter_gemm1_kernel<<<G + GB1, 256, 0, stream>>>(ei, E, K, CH, bcur, bkt,
                                                      x, W1, attS1, attD1, xl1, sd1, dd1, N, G);
    sort_finalize_kernel<<<K, 256, 0, stream>>>(bkt, boff, off, csrc, N);

    // ---- layer 1 aggregate (1 node/wave) ----
    agg1_kernel<<<(N + 3) / 4, 256, 0, stream>>>(xl1, sd1, dd1, b1, off, csrc, h1, N);

    // ---- layer 2 ----
    gemm2_kernel<<<(N + 63) / 64, 256, 0, stream>>>(h1, W2, attS2, attD2, xl2, sd2, dd2, N);
    agg2_kernel<<<(N + 3) / 4, 256, 0, stream>>>(xl2, sd2, dd2, b2, off, csrc, out, N);
}